// Round 1
// baseline (1547.518 us; speedup 1.0000x reference)
//
#include <hip/hip_runtime.h>
#include <hip/hip_bf16.h>
#include <float.h>

#define NNODES 100000
#define NEDGES 25000
#define NINC   800000
#define NH     4

// ---------------------------------------------------------------------------
// K1/K2: projection GEMM  feats[rows,128] = X[rows,128] @ W[128,128]
//        + fused attention score alpha[rows,4] = sum_c feats[r,h,c]*attn[h,c]
// 32-row tile, W (64KB) + X^T (16KB) in LDS, 4x4 per-thread tile, 2 blocks/CU.
__global__ __launch_bounds__(256, 2) void proj_kernel(
    const float* __restrict__ X, const float* __restrict__ W,
    const float* __restrict__ attn, float* __restrict__ feats,
    float* __restrict__ alphav, int nrows)
{
    __shared__ float sW[128 * 128];
    __shared__ float sXT[128 * 32];
    const int tid = threadIdx.x;

    // stage W row-major [k][n]
    {
        const float4* Wg = (const float4*)W;
        float4* sW4 = (float4*)sW;
#pragma unroll
        for (int j = 0; j < 16; ++j) sW4[tid + 256 * j] = Wg[tid + 256 * j];
    }
    const int row0 = blockIdx.x * 32;
    // stage X^T: sXT[k][r]
    {
        const int r = tid >> 3, kc = tid & 7;
        const int grow = row0 + r;
#pragma unroll
        for (int j = 0; j < 4; ++j) {
            const int k4 = kc + 8 * j;
            float4 v = make_float4(0.f, 0.f, 0.f, 0.f);
            if (grow < nrows) v = ((const float4*)X)[grow * 32 + k4];
            sXT[(4 * k4 + 0) * 32 + r] = v.x;
            sXT[(4 * k4 + 1) * 32 + r] = v.y;
            sXT[(4 * k4 + 2) * 32 + r] = v.z;
            sXT[(4 * k4 + 3) * 32 + r] = v.w;
        }
    }
    __syncthreads();

    const int c  = tid & 31;   // thread-col: output cols 4c..4c+3
    const int rg = tid >> 5;   // thread-row-group: rows 4rg..4rg+3
    float acc[4][4] = {};
#pragma unroll 4
    for (int k = 0; k < 128; ++k) {
        const float4 xv = *(const float4*)&sXT[k * 32 + 4 * rg];
        const float4 wv = *(const float4*)&sW[k * 128 + 4 * c];
        const float xr[4] = {xv.x, xv.y, xv.z, xv.w};
        const float wr[4] = {wv.x, wv.y, wv.z, wv.w};
#pragma unroll
        for (int a = 0; a < 4; ++a)
#pragma unroll
            for (int b = 0; b < 4; ++b)
                acc[a][b] = fmaf(xr[a], wr[b], acc[a][b]);
    }

    // write feats
#pragma unroll
    for (int rr = 0; rr < 4; ++rr) {
        const int grow = row0 + 4 * rg + rr;
        if (grow < nrows) {
            float4 o = make_float4(acc[rr][0], acc[rr][1], acc[rr][2], acc[rr][3]);
            ((float4*)feats)[grow * 32 + c] = o;
        }
    }

    // fused attention score: head h = c>>3, cols (4c..4c+3) % 32 within head
    const int h  = c >> 3;
    const int cc = (4 * c) & 31;
    const float a0 = attn[h * 32 + cc + 0];
    const float a1 = attn[h * 32 + cc + 1];
    const float a2 = attn[h * 32 + cc + 2];
    const float a3 = attn[h * 32 + cc + 3];
#pragma unroll
    for (int rr = 0; rr < 4; ++rr) {
        float p = acc[rr][0] * a0 + acc[rr][1] * a1 + acc[rr][2] * a2 + acc[rr][3] * a3;
        p += __shfl_xor(p, 1);
        p += __shfl_xor(p, 2);
        p += __shfl_xor(p, 4);
        if ((c & 7) == 0) {
            const int grow = row0 + 4 * rg + rr;
            if (grow < nrows) alphav[grow * 4 + h] = p;
        }
    }
}

// ---------------------------------------------------------------------------
// K3: edge CSR from sorted edge_idx. edge_start[e] = first i with eidx[i] >= e.
__global__ void csr_kernel(const int* __restrict__ eidx, int* __restrict__ edge_start)
{
    const int i = blockIdx.x * 256 + threadIdx.x;
    if (i >= NINC) return;
    const int cur  = eidx[i];
    const int prev = (i == 0) ? -1 : eidx[i - 1];
    for (int e = prev + 1; e <= cur; ++e) edge_start[e] = i;
    if (i == NINC - 1)
        for (int e = cur + 1; e <= NEDGES; ++e) edge_start[e] = NINC;
}

// ---------------------------------------------------------------------------
// K4: segment softmax per edge (one wave per edge). leaky_relu after softmax is
// identity (values strictly positive) -> skipped.
__global__ __launch_bounds__(256) void softmax_kernel(
    const int* __restrict__ nidx, const int* __restrict__ estart,
    const float* __restrict__ alpha_l, const float* __restrict__ alpha_r,
    float* __restrict__ alpha)
{
    const int wid  = (blockIdx.x * 256 + threadIdx.x) >> 6;  // edge id
    const int lane = threadIdx.x & 63;
    if (wid >= NEDGES) return;
    const int s = estart[wid], t = estart[wid + 1];
    if (s >= t) return;
    const float4 ar = ((const float4*)alpha_r)[wid];

    float m0 = -FLT_MAX, m1 = -FLT_MAX, m2 = -FLT_MAX, m3 = -FLT_MAX;
    for (int i = s + lane; i < t; i += 64) {
        const int n = nidx[i];
        const float4 al = ((const float4*)alpha_l)[n];
        m0 = fmaxf(m0, al.x + ar.x);
        m1 = fmaxf(m1, al.y + ar.y);
        m2 = fmaxf(m2, al.z + ar.z);
        m3 = fmaxf(m3, al.w + ar.w);
    }
#pragma unroll
    for (int d = 1; d < 64; d <<= 1) {
        m0 = fmaxf(m0, __shfl_xor(m0, d));
        m1 = fmaxf(m1, __shfl_xor(m1, d));
        m2 = fmaxf(m2, __shfl_xor(m2, d));
        m3 = fmaxf(m3, __shfl_xor(m3, d));
    }

    float s0 = 0.f, s1 = 0.f, s2 = 0.f, s3 = 0.f;
    for (int i = s + lane; i < t; i += 64) {
        const int n = nidx[i];
        const float4 al = ((const float4*)alpha_l)[n];
        const float e0 = __expf(al.x + ar.x - m0);
        const float e1 = __expf(al.y + ar.y - m1);
        const float e2 = __expf(al.z + ar.z - m2);
        const float e3 = __expf(al.w + ar.w - m3);
        s0 += e0; s1 += e1; s2 += e2; s3 += e3;
        ((float4*)alpha)[i] = make_float4(e0, e1, e2, e3);
    }
#pragma unroll
    for (int d = 1; d < 64; d <<= 1) {
        s0 += __shfl_xor(s0, d);
        s1 += __shfl_xor(s1, d);
        s2 += __shfl_xor(s2, d);
        s3 += __shfl_xor(s3, d);
    }
    const float i0 = 1.f / s0, i1 = 1.f / s1, i2 = 1.f / s2, i3 = 1.f / s3;
    for (int i = s + lane; i < t; i += 64) {
        float4 v = ((const float4*)alpha)[i];
        v.x *= i0; v.y *= i1; v.z *= i2; v.w *= i3;
        ((float4*)alpha)[i] = v;
    }
}

// ---------------------------------------------------------------------------
// K5: node->edge aggregation, one wave per edge, float2 per lane.
__global__ __launch_bounds__(256) void n2e_kernel(
    const int* __restrict__ nidx, const int* __restrict__ estart,
    const float* __restrict__ node_feats, const float* __restrict__ edge_feats,
    const float* __restrict__ alpha, float* __restrict__ edge_aggr)
{
    const int e    = (blockIdx.x * 256 + threadIdx.x) >> 6;
    const int lane = threadIdx.x & 63;
    if (e >= NEDGES) return;
    const int s = estart[e], t = estart[e + 1];
    const int h = lane >> 4;  // head of cols 2*lane..2*lane+1
    float2 acc = make_float2(0.f, 0.f);
    for (int i = s; i < t; ++i) {
        const int n  = nidx[i];
        const float a = alpha[i * 4 + h];
        const float2 v = ((const float2*)node_feats)[n * 64 + lane];
        acc.x = fmaf(v.x, a, acc.x);
        acc.y = fmaf(v.y, a, acc.y);
    }
    const float2 ef = ((const float2*)edge_feats)[e * 64 + lane];
    acc.x += ef.x;
    acc.y += ef.y;
    ((float2*)edge_aggr)[e * 64 + lane] = acc;
}

// ---------------------------------------------------------------------------
// K6a: init output with bias (also zero-fills for nodes with no incidences).
__global__ void init_out_kernel(float* __restrict__ out, const float* __restrict__ bias)
{
    const int g = blockIdx.x * 256 + threadIdx.x;  // float4 index, 3.2M total
    const float4 b = ((const float4*)bias)[g & 31];
    ((float4*)out)[g] = b;
}

// K6b: edge->node scatter with fp32 atomics. 32 lanes per incidence, float4/lane.
__global__ __launch_bounds__(256) void e2n_kernel(
    const int* __restrict__ nidx, const int* __restrict__ eidx,
    const float* __restrict__ edge_aggr, const float* __restrict__ alpha,
    float* __restrict__ out)
{
    const int gid = blockIdx.x * 256 + threadIdx.x;
    const int i   = gid >> 5;        // incidence
    const int cl  = gid & 31;        // float4 col index
    if (i >= NINC) return;
    const int e = eidx[i], n = nidx[i];
    const int h = cl >> 3;           // head of cols 4cl..4cl+3
    const float a = alpha[i * 4 + h];
    const float4 v = ((const float4*)edge_aggr)[e * 32 + cl];
    float* o = out + n * 128 + 4 * cl;
    atomicAdd(o + 0, v.x * a);
    atomicAdd(o + 1, v.y * a);
    atomicAdd(o + 2, v.z * a);
    atomicAdd(o + 3, v.w * a);
}

// ---------------------------------------------------------------------------
extern "C" void kernel_launch(void* const* d_in, const int* in_sizes, int n_in,
                              void* d_out, int out_size, void* d_ws, size_t ws_size,
                              hipStream_t stream)
{
    const float* x      = (const float*)d_in[0];
    const float* he     = (const float*)d_in[1];
    const int*   nidx   = (const int*)d_in[2];
    const int*   eidx   = (const int*)d_in[3];
    const float* Wn     = (const float*)d_in[4];
    const float* We     = (const float*)d_in[5];
    const float* attn_l = (const float*)d_in[6];
    const float* attn_r = (const float*)d_in[7];
    const float* bias   = (const float*)d_in[8];
    float* out = (float*)d_out;

    char* ws = (char*)d_ws;
    float* node_feats = (float*)ws;  ws += (size_t)NNODES * 128 * 4;
    float* edge_feats = (float*)ws;  ws += (size_t)NEDGES * 128 * 4;
    float* alpha_l    = (float*)ws;  ws += (size_t)NNODES * 4 * 4;
    float* alpha_r    = (float*)ws;  ws += (size_t)NEDGES * 4 * 4;
    float* alpha      = (float*)ws;  ws += (size_t)NINC * 4 * 4;
    float* edge_aggr  = (float*)ws;  ws += (size_t)NEDGES * 128 * 4;
    int*   edge_start = (int*)ws;    ws += (size_t)(NEDGES + 1) * 4;

    // K1/K2: projections + attention scores
    proj_kernel<<<(NNODES + 31) / 32, 256, 0, stream>>>(x, Wn, attn_l, node_feats, alpha_l, NNODES);
    proj_kernel<<<(NEDGES + 31) / 32, 256, 0, stream>>>(he, We, attn_r, edge_feats, alpha_r, NEDGES);
    // K3: edge CSR
    csr_kernel<<<(NINC + 255) / 256, 256, 0, stream>>>(eidx, edge_start);
    // K4: segment softmax
    softmax_kernel<<<(NEDGES * 64 + 255) / 256, 256, 0, stream>>>(nidx, edge_start, alpha_l, alpha_r, alpha);
    // K5: node->edge aggregation
    n2e_kernel<<<(NEDGES * 64 + 255) / 256, 256, 0, stream>>>(nidx, edge_start, node_feats, edge_feats, alpha, edge_aggr);
    // K6: init out with bias, then edge->node atomic scatter
    init_out_kernel<<<(NNODES * 32 + 255) / 256, 256, 0, stream>>>(out, bias);
    e2n_kernel<<<((size_t)NINC * 32 + 255) / 256, 256, 0, stream>>>(nidx, eidx, edge_aggr, alpha, out);
}

// Round 2
// 672.724 us; speedup vs baseline: 2.3004x; 2.3004x over previous
//
#include <hip/hip_runtime.h>
#include <hip/hip_bf16.h>
#include <float.h>

#define NNODES 100000
#define NEDGES 25000
#define NINC   800000
#define NH     4

// ---------------------------------------------------------------------------
// K1/K2: projection GEMM  feats[rows,128] = X[rows,128] @ W[128,128]
//        + fused attention score alpha[rows,4] = sum_c feats[r,h,c]*attn[h,c]
__global__ __launch_bounds__(256, 2) void proj_kernel(
    const float* __restrict__ X, const float* __restrict__ W,
    const float* __restrict__ attn, float* __restrict__ feats,
    float* __restrict__ alphav, int nrows)
{
    __shared__ float sW[128 * 128];
    __shared__ float sXT[128 * 32];
    const int tid = threadIdx.x;

    {
        const float4* Wg = (const float4*)W;
        float4* sW4 = (float4*)sW;
#pragma unroll
        for (int j = 0; j < 16; ++j) sW4[tid + 256 * j] = Wg[tid + 256 * j];
    }
    const int row0 = blockIdx.x * 32;
    {
        const int r = tid >> 3, kc = tid & 7;
        const int grow = row0 + r;
#pragma unroll
        for (int j = 0; j < 4; ++j) {
            const int k4 = kc + 8 * j;
            float4 v = make_float4(0.f, 0.f, 0.f, 0.f);
            if (grow < nrows) v = ((const float4*)X)[grow * 32 + k4];
            sXT[(4 * k4 + 0) * 32 + r] = v.x;
            sXT[(4 * k4 + 1) * 32 + r] = v.y;
            sXT[(4 * k4 + 2) * 32 + r] = v.z;
            sXT[(4 * k4 + 3) * 32 + r] = v.w;
        }
    }
    __syncthreads();

    const int c  = tid & 31;
    const int rg = tid >> 5;
    float acc[4][4] = {};
#pragma unroll 4
    for (int k = 0; k < 128; ++k) {
        const float4 xv = *(const float4*)&sXT[k * 32 + 4 * rg];
        const float4 wv = *(const float4*)&sW[k * 128 + 4 * c];
        const float xr[4] = {xv.x, xv.y, xv.z, xv.w};
        const float wr[4] = {wv.x, wv.y, wv.z, wv.w};
#pragma unroll
        for (int a = 0; a < 4; ++a)
#pragma unroll
            for (int b = 0; b < 4; ++b)
                acc[a][b] = fmaf(xr[a], wr[b], acc[a][b]);
    }

#pragma unroll
    for (int rr = 0; rr < 4; ++rr) {
        const int grow = row0 + 4 * rg + rr;
        if (grow < nrows) {
            float4 o = make_float4(acc[rr][0], acc[rr][1], acc[rr][2], acc[rr][3]);
            ((float4*)feats)[grow * 32 + c] = o;
        }
    }

    const int h  = c >> 3;
    const int cc = (4 * c) & 31;
    const float a0 = attn[h * 32 + cc + 0];
    const float a1 = attn[h * 32 + cc + 1];
    const float a2 = attn[h * 32 + cc + 2];
    const float a3 = attn[h * 32 + cc + 3];
#pragma unroll
    for (int rr = 0; rr < 4; ++rr) {
        float p = acc[rr][0] * a0 + acc[rr][1] * a1 + acc[rr][2] * a2 + acc[rr][3] * a3;
        p += __shfl_xor(p, 1);
        p += __shfl_xor(p, 2);
        p += __shfl_xor(p, 4);
        if ((c & 7) == 0) {
            const int grow = row0 + 4 * rg + rr;
            if (grow < nrows) alphav[grow * 4 + h] = p;
        }
    }
}

// ---------------------------------------------------------------------------
// K3: edge CSR from sorted edge_idx.
__global__ void csr_kernel(const int* __restrict__ eidx, int* __restrict__ edge_start)
{
    const int i = blockIdx.x * 256 + threadIdx.x;
    if (i >= NINC) return;
    const int cur  = eidx[i];
    const int prev = (i == 0) ? -1 : eidx[i - 1];
    for (int e = prev + 1; e <= cur; ++e) edge_start[e] = i;
    if (i == NINC - 1)
        for (int e = cur + 1; e <= NEDGES; ++e) edge_start[e] = NINC;
}

// ---------------------------------------------------------------------------
// K4: segment softmax per edge (one wave per edge).
__global__ __launch_bounds__(256) void softmax_kernel(
    const int* __restrict__ nidx, const int* __restrict__ estart,
    const float* __restrict__ alpha_l, const float* __restrict__ alpha_r,
    float* __restrict__ alpha)
{
    const int wid  = (blockIdx.x * 256 + threadIdx.x) >> 6;
    const int lane = threadIdx.x & 63;
    if (wid >= NEDGES) return;
    const int s = estart[wid], t = estart[wid + 1];
    if (s >= t) return;
    const float4 ar = ((const float4*)alpha_r)[wid];

    float m0 = -FLT_MAX, m1 = -FLT_MAX, m2 = -FLT_MAX, m3 = -FLT_MAX;
    for (int i = s + lane; i < t; i += 64) {
        const int n = nidx[i];
        const float4 al = ((const float4*)alpha_l)[n];
        m0 = fmaxf(m0, al.x + ar.x);
        m1 = fmaxf(m1, al.y + ar.y);
        m2 = fmaxf(m2, al.z + ar.z);
        m3 = fmaxf(m3, al.w + ar.w);
    }
#pragma unroll
    for (int d = 1; d < 64; d <<= 1) {
        m0 = fmaxf(m0, __shfl_xor(m0, d));
        m1 = fmaxf(m1, __shfl_xor(m1, d));
        m2 = fmaxf(m2, __shfl_xor(m2, d));
        m3 = fmaxf(m3, __shfl_xor(m3, d));
    }

    float s0 = 0.f, s1 = 0.f, s2 = 0.f, s3 = 0.f;
    for (int i = s + lane; i < t; i += 64) {
        const int n = nidx[i];
        const float4 al = ((const float4*)alpha_l)[n];
        const float e0 = __expf(al.x + ar.x - m0);
        const float e1 = __expf(al.y + ar.y - m1);
        const float e2 = __expf(al.z + ar.z - m2);
        const float e3 = __expf(al.w + ar.w - m3);
        s0 += e0; s1 += e1; s2 += e2; s3 += e3;
        ((float4*)alpha)[i] = make_float4(e0, e1, e2, e3);
    }
#pragma unroll
    for (int d = 1; d < 64; d <<= 1) {
        s0 += __shfl_xor(s0, d);
        s1 += __shfl_xor(s1, d);
        s2 += __shfl_xor(s2, d);
        s3 += __shfl_xor(s3, d);
    }
    const float i0 = 1.f / s0, i1 = 1.f / s1, i2 = 1.f / s2, i3 = 1.f / s3;
    for (int i = s + lane; i < t; i += 64) {
        float4 v = ((const float4*)alpha)[i];
        v.x *= i0; v.y *= i1; v.z *= i2; v.w *= i3;
        ((float4*)alpha)[i] = v;
    }
}

// ---------------------------------------------------------------------------
// K5: node->edge aggregation, one wave per edge, float2 per lane.
__global__ __launch_bounds__(256) void n2e_kernel(
    const int* __restrict__ nidx, const int* __restrict__ estart,
    const float* __restrict__ node_feats, const float* __restrict__ edge_feats,
    const float* __restrict__ alpha, float* __restrict__ edge_aggr)
{
    const int e    = (blockIdx.x * 256 + threadIdx.x) >> 6;
    const int lane = threadIdx.x & 63;
    if (e >= NEDGES) return;
    const int s = estart[e], t = estart[e + 1];
    const int h = lane >> 4;
    float2 acc = make_float2(0.f, 0.f);
    for (int i = s; i < t; ++i) {
        const int n  = nidx[i];
        const float a = alpha[i * 4 + h];
        const float2 v = ((const float2*)node_feats)[n * 64 + lane];
        acc.x = fmaf(v.x, a, acc.x);
        acc.y = fmaf(v.y, a, acc.y);
    }
    const float2 ef = ((const float2*)edge_feats)[e * 64 + lane];
    acc.x += ef.x;
    acc.y += ef.y;
    ((float2*)edge_aggr)[e * 64 + lane] = acc;
}

// ---------------------------------------------------------------------------
// Counting sort of incidences by node id.
// K6a: zero histogram
__global__ void zero_kernel(int* __restrict__ p, int n)
{
    const int i = blockIdx.x * 256 + threadIdx.x;
    if (i < n) p[i] = 0;
}

// K6b: node-degree histogram
__global__ void hist_kernel(const int* __restrict__ nidx, int* __restrict__ cnt)
{
    const int i = blockIdx.x * 256 + threadIdx.x;
    if (i < NINC) atomicAdd(&cnt[nidx[i]], 1);
}

// K6c: single-block exclusive scan (1024 threads, ~98 elems each)
__global__ __launch_bounds__(1024) void scan_kernel(
    const int* __restrict__ cnt, int* __restrict__ node_start, int* __restrict__ cursor)
{
    __shared__ int part[1024];
    const int tid = threadIdx.x;
    const int CH = (NNODES + 1023) / 1024;
    const int base = tid * CH;
    int sum = 0;
    for (int j = 0; j < CH; ++j) {
        const int idx = base + j;
        if (idx < NNODES) sum += cnt[idx];
    }
    part[tid] = sum;
    __syncthreads();
    for (int d = 1; d < 1024; d <<= 1) {
        const int v = (tid >= d) ? part[tid - d] : 0;
        __syncthreads();
        part[tid] += v;
        __syncthreads();
    }
    int run = (tid == 0) ? 0 : part[tid - 1];
    for (int j = 0; j < CH; ++j) {
        const int idx = base + j;
        if (idx < NNODES) {
            node_start[idx] = run;
            cursor[idx]     = run;
            run += cnt[idx];
        }
    }
    if (tid == 0) node_start[NNODES] = NINC;
}

// K6d: scatter incidence ids into node-sorted order
__global__ void nsort_kernel(const int* __restrict__ nidx, int* __restrict__ cursor,
                             int* __restrict__ sorted)
{
    const int i = blockIdx.x * 256 + threadIdx.x;
    if (i >= NINC) return;
    const int pos = atomicAdd(&cursor[nidx[i]], 1);
    sorted[pos] = i;
}

// ---------------------------------------------------------------------------
// K7: edge->node aggregation as a GATHER. One wave per node, float2 per lane.
__global__ __launch_bounds__(256) void e2n_gather_kernel(
    const int* __restrict__ sorted, const int* __restrict__ node_start,
    const int* __restrict__ eidx, const float* __restrict__ edge_aggr,
    const float* __restrict__ alpha, const float* __restrict__ bias,
    float* __restrict__ out)
{
    const int n    = (blockIdx.x * 256 + threadIdx.x) >> 6;
    const int lane = threadIdx.x & 63;
    if (n >= NNODES) return;
    const int s = node_start[n], t = node_start[n + 1];
    const int h = lane >> 4;
    float2 acc = make_float2(0.f, 0.f);
    for (int j = s; j < t; ++j) {
        const int i = sorted[j];
        const int e = eidx[i];
        const float a = alpha[i * 4 + h];
        const float2 v = ((const float2*)edge_aggr)[e * 64 + lane];
        acc.x = fmaf(v.x, a, acc.x);
        acc.y = fmaf(v.y, a, acc.y);
    }
    const float2 b = ((const float2*)bias)[lane];
    acc.x += b.x;
    acc.y += b.y;
    ((float2*)out)[n * 64 + lane] = acc;
}

// ---------------------------------------------------------------------------
extern "C" void kernel_launch(void* const* d_in, const int* in_sizes, int n_in,
                              void* d_out, int out_size, void* d_ws, size_t ws_size,
                              hipStream_t stream)
{
    const float* x      = (const float*)d_in[0];
    const float* he     = (const float*)d_in[1];
    const int*   nidx   = (const int*)d_in[2];
    const int*   eidx   = (const int*)d_in[3];
    const float* Wn     = (const float*)d_in[4];
    const float* We     = (const float*)d_in[5];
    const float* attn_l = (const float*)d_in[6];
    const float* attn_r = (const float*)d_in[7];
    const float* bias   = (const float*)d_in[8];
    float* out = (float*)d_out;

    char* ws = (char*)d_ws;
    float* node_feats = (float*)ws;  ws += (size_t)NNODES * 128 * 4;
    float* edge_feats = (float*)ws;  ws += (size_t)NEDGES * 128 * 4;
    float* alpha_l    = (float*)ws;  ws += (size_t)NNODES * 4 * 4;
    float* alpha_r    = (float*)ws;  ws += (size_t)NEDGES * 4 * 4;
    float* alpha      = (float*)ws;  ws += (size_t)NINC * 4 * 4;
    float* edge_aggr  = (float*)ws;  ws += (size_t)NEDGES * 128 * 4;
    int*   edge_start = (int*)ws;    ws += (size_t)(NEDGES + 4) * 4;
    int*   cnt        = (int*)ws;    ws += (size_t)NNODES * 4;
    int*   node_start = (int*)ws;    ws += (size_t)(NNODES + 4) * 4;
    int*   cursor     = (int*)ws;    ws += (size_t)NNODES * 4;
    int*   sorted     = (int*)ws;    ws += (size_t)NINC * 4;

    // projections + attention scores
    proj_kernel<<<(NNODES + 31) / 32, 256, 0, stream>>>(x, Wn, attn_l, node_feats, alpha_l, NNODES);
    proj_kernel<<<(NEDGES + 31) / 32, 256, 0, stream>>>(he, We, attn_r, edge_feats, alpha_r, NEDGES);
    // edge CSR (sorted input)
    csr_kernel<<<(NINC + 255) / 256, 256, 0, stream>>>(eidx, edge_start);
    // node counting-sort: hist -> scan -> scatter
    zero_kernel<<<(NNODES + 255) / 256, 256, 0, stream>>>(cnt, NNODES);
    hist_kernel<<<(NINC + 255) / 256, 256, 0, stream>>>(nidx, cnt);
    scan_kernel<<<1, 1024, 0, stream>>>(cnt, node_start, cursor);
    nsort_kernel<<<(NINC + 255) / 256, 256, 0, stream>>>(nidx, cursor, sorted);
    // segment softmax
    softmax_kernel<<<(NEDGES * 64 + 255) / 256, 256, 0, stream>>>(nidx, edge_start, alpha_l, alpha_r, alpha);
    // node->edge aggregation
    n2e_kernel<<<(NEDGES * 64 + 255) / 256, 256, 0, stream>>>(nidx, edge_start, node_feats, edge_feats, alpha, edge_aggr);
    // edge->node aggregation (gather)
    e2n_gather_kernel<<<(NNODES * 64 + 255) / 256, 256, 0, stream>>>(sorted, node_start, eidx, edge_aggr, alpha, bias, out);
}

// Round 3
// 443.574 us; speedup vs baseline: 3.4887x; 1.5166x over previous
//
#include <hip/hip_runtime.h>
#include <hip/hip_bf16.h>
#include <float.h>

#define NNODES 100000
#define NEDGES 25000
#define NINC   800000
#define NH     4

// ---------------------------------------------------------------------------
// K1/K2: projection GEMM  feats[rows,128] = X[rows,128] @ W[128,128]
//        + fused attention score alpha[rows,4] = sum_c feats[r,h,c]*attn[h,c]
__global__ __launch_bounds__(256, 2) void proj_kernel(
    const float* __restrict__ X, const float* __restrict__ W,
    const float* __restrict__ attn, float* __restrict__ feats,
    float* __restrict__ alphav, int nrows)
{
    __shared__ float sW[128 * 128];
    __shared__ float sXT[128 * 32];
    const int tid = threadIdx.x;

    {
        const float4* Wg = (const float4*)W;
        float4* sW4 = (float4*)sW;
#pragma unroll
        for (int j = 0; j < 16; ++j) sW4[tid + 256 * j] = Wg[tid + 256 * j];
    }
    const int row0 = blockIdx.x * 32;
    {
        const int r = tid >> 3, kc = tid & 7;
        const int grow = row0 + r;
#pragma unroll
        for (int j = 0; j < 4; ++j) {
            const int k4 = kc + 8 * j;
            float4 v = make_float4(0.f, 0.f, 0.f, 0.f);
            if (grow < nrows) v = ((const float4*)X)[grow * 32 + k4];
            sXT[(4 * k4 + 0) * 32 + r] = v.x;
            sXT[(4 * k4 + 1) * 32 + r] = v.y;
            sXT[(4 * k4 + 2) * 32 + r] = v.z;
            sXT[(4 * k4 + 3) * 32 + r] = v.w;
        }
    }
    __syncthreads();

    const int c  = tid & 31;
    const int rg = tid >> 5;
    float acc[4][4] = {};
#pragma unroll 4
    for (int k = 0; k < 128; ++k) {
        const float4 xv = *(const float4*)&sXT[k * 32 + 4 * rg];
        const float4 wv = *(const float4*)&sW[k * 128 + 4 * c];
        const float xr[4] = {xv.x, xv.y, xv.z, xv.w};
        const float wr[4] = {wv.x, wv.y, wv.z, wv.w};
#pragma unroll
        for (int a = 0; a < 4; ++a)
#pragma unroll
            for (int b = 0; b < 4; ++b)
                acc[a][b] = fmaf(xr[a], wr[b], acc[a][b]);
    }

#pragma unroll
    for (int rr = 0; rr < 4; ++rr) {
        const int grow = row0 + 4 * rg + rr;
        if (grow < nrows) {
            float4 o = make_float4(acc[rr][0], acc[rr][1], acc[rr][2], acc[rr][3]);
            ((float4*)feats)[grow * 32 + c] = o;
        }
    }

    const int h  = c >> 3;
    const int cc = (4 * c) & 31;
    const float a0 = attn[h * 32 + cc + 0];
    const float a1 = attn[h * 32 + cc + 1];
    const float a2 = attn[h * 32 + cc + 2];
    const float a3 = attn[h * 32 + cc + 3];
#pragma unroll
    for (int rr = 0; rr < 4; ++rr) {
        float p = acc[rr][0] * a0 + acc[rr][1] * a1 + acc[rr][2] * a2 + acc[rr][3] * a3;
        p += __shfl_xor(p, 1);
        p += __shfl_xor(p, 2);
        p += __shfl_xor(p, 4);
        if ((c & 7) == 0) {
            const int grow = row0 + 4 * rg + rr;
            if (grow < nrows) alphav[grow * 4 + h] = p;
        }
    }
}

// ---------------------------------------------------------------------------
// K3: edge CSR from sorted edge_idx.
__global__ void csr_kernel(const int* __restrict__ eidx, int* __restrict__ edge_start)
{
    const int i = blockIdx.x * 256 + threadIdx.x;
    if (i >= NINC) return;
    const int cur  = eidx[i];
    const int prev = (i == 0) ? -1 : eidx[i - 1];
    for (int e = prev + 1; e <= cur; ++e) edge_start[e] = i;
    if (i == NINC - 1)
        for (int e = cur + 1; e <= NEDGES; ++e) edge_start[e] = NINC;
}

// ---------------------------------------------------------------------------
// K4: segment softmax per edge (one wave per edge).
__global__ __launch_bounds__(256) void softmax_kernel(
    const int* __restrict__ nidx, const int* __restrict__ estart,
    const float* __restrict__ alpha_l, const float* __restrict__ alpha_r,
    float* __restrict__ alpha)
{
    const int wid  = (blockIdx.x * 256 + threadIdx.x) >> 6;
    const int lane = threadIdx.x & 63;
    if (wid >= NEDGES) return;
    const int s = estart[wid], t = estart[wid + 1];
    if (s >= t) return;
    const float4 ar = ((const float4*)alpha_r)[wid];

    float m0 = -FLT_MAX, m1 = -FLT_MAX, m2 = -FLT_MAX, m3 = -FLT_MAX;
    for (int i = s + lane; i < t; i += 64) {
        const int n = nidx[i];
        const float4 al = ((const float4*)alpha_l)[n];
        m0 = fmaxf(m0, al.x + ar.x);
        m1 = fmaxf(m1, al.y + ar.y);
        m2 = fmaxf(m2, al.z + ar.z);
        m3 = fmaxf(m3, al.w + ar.w);
    }
#pragma unroll
    for (int d = 1; d < 64; d <<= 1) {
        m0 = fmaxf(m0, __shfl_xor(m0, d));
        m1 = fmaxf(m1, __shfl_xor(m1, d));
        m2 = fmaxf(m2, __shfl_xor(m2, d));
        m3 = fmaxf(m3, __shfl_xor(m3, d));
    }

    float s0 = 0.f, s1 = 0.f, s2 = 0.f, s3 = 0.f;
    for (int i = s + lane; i < t; i += 64) {
        const int n = nidx[i];
        const float4 al = ((const float4*)alpha_l)[n];
        const float e0 = __expf(al.x + ar.x - m0);
        const float e1 = __expf(al.y + ar.y - m1);
        const float e2 = __expf(al.z + ar.z - m2);
        const float e3 = __expf(al.w + ar.w - m3);
        s0 += e0; s1 += e1; s2 += e2; s3 += e3;
        ((float4*)alpha)[i] = make_float4(e0, e1, e2, e3);
    }
#pragma unroll
    for (int d = 1; d < 64; d <<= 1) {
        s0 += __shfl_xor(s0, d);
        s1 += __shfl_xor(s1, d);
        s2 += __shfl_xor(s2, d);
        s3 += __shfl_xor(s3, d);
    }
    const float i0 = 1.f / s0, i1 = 1.f / s1, i2 = 1.f / s2, i3 = 1.f / s3;
    for (int i = s + lane; i < t; i += 64) {
        float4 v = ((const float4*)alpha)[i];
        v.x *= i0; v.y *= i1; v.z *= i2; v.w *= i3;
        ((float4*)alpha)[i] = v;
    }
}

// ---------------------------------------------------------------------------
// K5: node->edge aggregation, one wave per edge, float2 per lane.
__global__ __launch_bounds__(256) void n2e_kernel(
    const int* __restrict__ nidx, const int* __restrict__ estart,
    const float* __restrict__ node_feats, const float* __restrict__ edge_feats,
    const float* __restrict__ alpha, float* __restrict__ edge_aggr)
{
    const int e    = (blockIdx.x * 256 + threadIdx.x) >> 6;
    const int lane = threadIdx.x & 63;
    if (e >= NEDGES) return;
    const int s = estart[e], t = estart[e + 1];
    const int h = lane >> 4;
    float2 acc = make_float2(0.f, 0.f);
    for (int i = s; i < t; ++i) {
        const int n  = nidx[i];
        const float a = alpha[i * 4 + h];
        const float2 v = ((const float2*)node_feats)[n * 64 + lane];
        acc.x = fmaf(v.x, a, acc.x);
        acc.y = fmaf(v.y, a, acc.y);
    }
    const float2 ef = ((const float2*)edge_feats)[e * 64 + lane];
    acc.x += ef.x;
    acc.y += ef.y;
    ((float2*)edge_aggr)[e * 64 + lane] = acc;
}

// ---------------------------------------------------------------------------
// Counting sort of incidences by node id (unordered slot allocation).
// K6a: zero histogram + global cursor
__global__ void zero_kernel(int* __restrict__ p, int n)
{
    const int i = blockIdx.x * 256 + threadIdx.x;
    if (i < n) p[i] = 0;
}

// K6b: node-degree histogram
__global__ void hist_kernel(const int* __restrict__ nidx, int* __restrict__ cnt)
{
    const int i = blockIdx.x * 256 + threadIdx.x;
    if (i < NINC) atomicAdd(&cnt[nidx[i]], 1);
}

// K6c: wave-aggregated slot allocation. Node order in `sorted` is arbitrary;
// each node just needs a private contiguous range [node_start, node_start+cnt).
__global__ __launch_bounds__(256) void assign_kernel(
    const int* __restrict__ cnt, int* __restrict__ node_start,
    int* __restrict__ cursor, int* __restrict__ gcursor)
{
    const int n    = blockIdx.x * 256 + threadIdx.x;
    const int lane = threadIdx.x & 63;
    const int c = (n < NNODES) ? cnt[n] : 0;
    // inclusive scan of c across the wave
    int incl = c;
#pragma unroll
    for (int d = 1; d < 64; d <<= 1) {
        const int v = __shfl_up(incl, d);
        if (lane >= d) incl += v;
    }
    const int total = __shfl(incl, 63);
    int base = 0;
    if (lane == 63) base = atomicAdd(gcursor, total);
    base = __shfl(base, 63);
    const int excl = incl - c;
    if (n < NNODES) {
        node_start[n] = base + excl;
        cursor[n]     = base + excl;
    }
}

// K6d: scatter incidence ids into node-sorted order
__global__ void nsort_kernel(const int* __restrict__ nidx, int* __restrict__ cursor,
                             int* __restrict__ sorted)
{
    const int i = blockIdx.x * 256 + threadIdx.x;
    if (i >= NINC) return;
    const int pos = atomicAdd(&cursor[nidx[i]], 1);
    sorted[pos] = i;
}

// ---------------------------------------------------------------------------
// K7: edge->node aggregation as a GATHER. One wave per node, float2 per lane.
__global__ __launch_bounds__(256) void e2n_gather_kernel(
    const int* __restrict__ sorted, const int* __restrict__ node_start,
    const int* __restrict__ cnt, const int* __restrict__ eidx,
    const float* __restrict__ edge_aggr, const float* __restrict__ alpha,
    const float* __restrict__ bias, float* __restrict__ out)
{
    const int n    = (blockIdx.x * 256 + threadIdx.x) >> 6;
    const int lane = threadIdx.x & 63;
    if (n >= NNODES) return;
    const int s = node_start[n], t = s + cnt[n];
    const int h = lane >> 4;
    float2 acc = make_float2(0.f, 0.f);
    for (int j = s; j < t; ++j) {
        const int i = sorted[j];
        const int e = eidx[i];
        const float a = alpha[i * 4 + h];
        const float2 v = ((const float2*)edge_aggr)[e * 64 + lane];
        acc.x = fmaf(v.x, a, acc.x);
        acc.y = fmaf(v.y, a, acc.y);
    }
    const float2 b = ((const float2*)bias)[lane];
    acc.x += b.x;
    acc.y += b.y;
    ((float2*)out)[n * 64 + lane] = acc;
}

// ---------------------------------------------------------------------------
extern "C" void kernel_launch(void* const* d_in, const int* in_sizes, int n_in,
                              void* d_out, int out_size, void* d_ws, size_t ws_size,
                              hipStream_t stream)
{
    const float* x      = (const float*)d_in[0];
    const float* he     = (const float*)d_in[1];
    const int*   nidx   = (const int*)d_in[2];
    const int*   eidx   = (const int*)d_in[3];
    const float* Wn     = (const float*)d_in[4];
    const float* We     = (const float*)d_in[5];
    const float* attn_l = (const float*)d_in[6];
    const float* attn_r = (const float*)d_in[7];
    const float* bias   = (const float*)d_in[8];
    float* out = (float*)d_out;

    char* ws = (char*)d_ws;
    float* node_feats = (float*)ws;  ws += (size_t)NNODES * 128 * 4;
    float* edge_feats = (float*)ws;  ws += (size_t)NEDGES * 128 * 4;
    float* alpha_l    = (float*)ws;  ws += (size_t)NNODES * 4 * 4;
    float* alpha_r    = (float*)ws;  ws += (size_t)NEDGES * 4 * 4;
    float* alpha      = (float*)ws;  ws += (size_t)NINC * 4 * 4;
    float* edge_aggr  = (float*)ws;  ws += (size_t)NEDGES * 128 * 4;
    int*   edge_start = (int*)ws;    ws += (size_t)(NEDGES + 4) * 4;
    int*   cnt        = (int*)ws;    ws += (size_t)(NNODES + 4) * 4;  // +gcursor
    int*   node_start = (int*)ws;    ws += (size_t)(NNODES + 4) * 4;
    int*   cursor     = (int*)ws;    ws += (size_t)NNODES * 4;
    int*   sorted     = (int*)ws;    ws += (size_t)NINC * 4;
    int*   gcursor    = cnt + NNODES;

    // projections + attention scores
    proj_kernel<<<(NNODES + 31) / 32, 256, 0, stream>>>(x, Wn, attn_l, node_feats, alpha_l, NNODES);
    proj_kernel<<<(NEDGES + 31) / 32, 256, 0, stream>>>(he, We, attn_r, edge_feats, alpha_r, NEDGES);
    // edge CSR (sorted input)
    csr_kernel<<<(NINC + 255) / 256, 256, 0, stream>>>(eidx, edge_start);
    // node counting-sort: zero -> hist -> assign -> scatter
    zero_kernel<<<(NNODES + 1 + 255) / 256, 256, 0, stream>>>(cnt, NNODES + 1);
    hist_kernel<<<(NINC + 255) / 256, 256, 0, stream>>>(nidx, cnt);
    assign_kernel<<<(NNODES + 255) / 256, 256, 0, stream>>>(cnt, node_start, cursor, gcursor);
    nsort_kernel<<<(NINC + 255) / 256, 256, 0, stream>>>(nidx, cursor, sorted);
    // segment softmax
    softmax_kernel<<<(NEDGES * 64 + 255) / 256, 256, 0, stream>>>(nidx, edge_start, alpha_l, alpha_r, alpha);
    // node->edge aggregation
    n2e_kernel<<<(NEDGES * 64 + 255) / 256, 256, 0, stream>>>(nidx, edge_start, node_feats, edge_feats, alpha, edge_aggr);
    // edge->node aggregation (gather)
    e2n_gather_kernel<<<(NNODES * 64 + 255) / 256, 256, 0, stream>>>(sorted, node_start, cnt, eidx, edge_aggr, alpha, bias, out);
}

// Round 4
// 379.863 us; speedup vs baseline: 4.0739x; 1.1677x over previous
//
#include <hip/hip_runtime.h>
#include <hip/hip_bf16.h>
#include <float.h>

#define NNODES 100000
#define NEDGES 25000
#define NINC   800000
#define NH     4

// bf16 <-> f32 helpers (RNE pack, shift unpack)
__device__ __forceinline__ float bf2f(unsigned int u16)
{
    union { unsigned int u; float f; } c;
    c.u = u16 << 16;
    return c.f;
}
__device__ __forceinline__ unsigned int f2bf(float f)
{
    union { float f; unsigned int u; } c;
    c.f = f;
    return (c.u + 0x7FFFu + ((c.u >> 16) & 1u)) >> 16;
}

// ---------------------------------------------------------------------------
// K1/K2: projection GEMM  feats[rows,128] = X[rows,128] @ W[128,128]  (bf16 out)
//        + fused attention score alpha[rows,4]
__global__ __launch_bounds__(256, 2) void proj_kernel(
    const float* __restrict__ X, const float* __restrict__ W,
    const float* __restrict__ attn, ushort* __restrict__ feats_bf,
    float* __restrict__ alphav, int nrows)
{
    __shared__ float sW[128 * 128];
    __shared__ float sXT[128 * 32];
    const int tid = threadIdx.x;

    {
        const float4* Wg = (const float4*)W;
        float4* sW4 = (float4*)sW;
#pragma unroll
        for (int j = 0; j < 16; ++j) sW4[tid + 256 * j] = Wg[tid + 256 * j];
    }
    const int row0 = blockIdx.x * 32;
    {
        const int r = tid >> 3, kc = tid & 7;
        const int grow = row0 + r;
#pragma unroll
        for (int j = 0; j < 4; ++j) {
            const int k4 = kc + 8 * j;
            float4 v = make_float4(0.f, 0.f, 0.f, 0.f);
            if (grow < nrows) v = ((const float4*)X)[grow * 32 + k4];
            sXT[(4 * k4 + 0) * 32 + r] = v.x;
            sXT[(4 * k4 + 1) * 32 + r] = v.y;
            sXT[(4 * k4 + 2) * 32 + r] = v.z;
            sXT[(4 * k4 + 3) * 32 + r] = v.w;
        }
    }
    __syncthreads();

    const int c  = tid & 31;
    const int rg = tid >> 5;
    float acc[4][4] = {};
#pragma unroll 4
    for (int k = 0; k < 128; ++k) {
        const float4 xv = *(const float4*)&sXT[k * 32 + 4 * rg];
        const float4 wv = *(const float4*)&sW[k * 128 + 4 * c];
        const float xr[4] = {xv.x, xv.y, xv.z, xv.w};
        const float wr[4] = {wv.x, wv.y, wv.z, wv.w};
#pragma unroll
        for (int a = 0; a < 4; ++a)
#pragma unroll
            for (int b = 0; b < 4; ++b)
                acc[a][b] = fmaf(xr[a], wr[b], acc[a][b]);
    }

#pragma unroll
    for (int rr = 0; rr < 4; ++rr) {
        const int grow = row0 + 4 * rg + rr;
        if (grow < nrows) {
            ushort4 o;
            o.x = (ushort)f2bf(acc[rr][0]);
            o.y = (ushort)f2bf(acc[rr][1]);
            o.z = (ushort)f2bf(acc[rr][2]);
            o.w = (ushort)f2bf(acc[rr][3]);
            ((ushort4*)feats_bf)[grow * 32 + c] = o;
        }
    }

    const int h  = c >> 3;
    const int cc = (4 * c) & 31;
    const float a0 = attn[h * 32 + cc + 0];
    const float a1 = attn[h * 32 + cc + 1];
    const float a2 = attn[h * 32 + cc + 2];
    const float a3 = attn[h * 32 + cc + 3];
#pragma unroll
    for (int rr = 0; rr < 4; ++rr) {
        float p = acc[rr][0] * a0 + acc[rr][1] * a1 + acc[rr][2] * a2 + acc[rr][3] * a3;
        p += __shfl_xor(p, 1);
        p += __shfl_xor(p, 2);
        p += __shfl_xor(p, 4);
        if ((c & 7) == 0) {
            const int grow = row0 + 4 * rg + rr;
            if (grow < nrows) alphav[grow * 4 + h] = p;
        }
    }
}

// ---------------------------------------------------------------------------
// K3: edge CSR from sorted edge_idx.
__global__ void csr_kernel(const int* __restrict__ eidx, int* __restrict__ edge_start)
{
    const int i = blockIdx.x * 256 + threadIdx.x;
    if (i >= NINC) return;
    const int cur  = eidx[i];
    const int prev = (i == 0) ? -1 : eidx[i - 1];
    for (int e = prev + 1; e <= cur; ++e) edge_start[e] = i;
    if (i == NINC - 1)
        for (int e = cur + 1; e <= NEDGES; ++e) edge_start[e] = NINC;
}

// ---------------------------------------------------------------------------
// K4: segment softmax, 2 passes. Writes UNNORMALIZED ex[I,4] and inv_denom[E,4].
__global__ __launch_bounds__(256) void softmax_kernel(
    const int* __restrict__ nidx, const int* __restrict__ estart,
    const float* __restrict__ alpha_l, const float* __restrict__ alpha_r,
    float* __restrict__ ex, float* __restrict__ inv_denom)
{
    const int wid  = (blockIdx.x * 256 + threadIdx.x) >> 6;
    const int lane = threadIdx.x & 63;
    if (wid >= NEDGES) return;
    const int s = estart[wid], t = estart[wid + 1];
    if (s >= t) return;
    const float4 ar = ((const float4*)alpha_r)[wid];

    float m0 = -FLT_MAX, m1 = -FLT_MAX, m2 = -FLT_MAX, m3 = -FLT_MAX;
    for (int i = s + lane; i < t; i += 64) {
        const int n = nidx[i];
        const float4 al = ((const float4*)alpha_l)[n];
        m0 = fmaxf(m0, al.x + ar.x);
        m1 = fmaxf(m1, al.y + ar.y);
        m2 = fmaxf(m2, al.z + ar.z);
        m3 = fmaxf(m3, al.w + ar.w);
    }
#pragma unroll
    for (int d = 1; d < 64; d <<= 1) {
        m0 = fmaxf(m0, __shfl_xor(m0, d));
        m1 = fmaxf(m1, __shfl_xor(m1, d));
        m2 = fmaxf(m2, __shfl_xor(m2, d));
        m3 = fmaxf(m3, __shfl_xor(m3, d));
    }

    float s0 = 0.f, s1 = 0.f, s2 = 0.f, s3 = 0.f;
    for (int i = s + lane; i < t; i += 64) {
        const int n = nidx[i];
        const float4 al = ((const float4*)alpha_l)[n];
        const float e0 = __expf(al.x + ar.x - m0);
        const float e1 = __expf(al.y + ar.y - m1);
        const float e2 = __expf(al.z + ar.z - m2);
        const float e3 = __expf(al.w + ar.w - m3);
        s0 += e0; s1 += e1; s2 += e2; s3 += e3;
        ((float4*)ex)[i] = make_float4(e0, e1, e2, e3);
    }
#pragma unroll
    for (int d = 1; d < 64; d <<= 1) {
        s0 += __shfl_xor(s0, d);
        s1 += __shfl_xor(s1, d);
        s2 += __shfl_xor(s2, d);
        s3 += __shfl_xor(s3, d);
    }
    if (lane == 0)
        ((float4*)inv_denom)[wid] = make_float4(1.f / s0, 1.f / s1, 1.f / s2, 1.f / s3);
}

// ---------------------------------------------------------------------------
// K5: node->edge aggregation, one wave per edge, 2 bf16 cols per lane.
// edge_aggr_bf[e] = bf16( inv_denom[e] * sum_i ex[i]*node_feats[nidx[i]] + edge_feats[e] )
__global__ __launch_bounds__(256) void n2e_kernel(
    const int* __restrict__ nidx, const int* __restrict__ estart,
    const unsigned int* __restrict__ node_feats_bf,
    const unsigned int* __restrict__ edge_feats_bf,
    const float* __restrict__ ex, const float* __restrict__ inv_denom,
    unsigned int* __restrict__ edge_aggr_bf)
{
    const int e    = (blockIdx.x * 256 + threadIdx.x) >> 6;
    const int lane = threadIdx.x & 63;
    if (e >= NEDGES) return;
    const int s = estart[e], t = estart[e + 1];
    const int h = lane >> 4;
    const float invd = inv_denom[e * 4 + h];
    float ax = 0.f, ay = 0.f;
    for (int i = s; i < t; ++i) {
        const int n  = nidx[i];
        const float a = ex[i * 4 + h];
        const unsigned int v = node_feats_bf[n * 64 + lane];
        ax = fmaf(bf2f(v & 0xffffu), a, ax);
        ay = fmaf(bf2f(v >> 16), a, ay);
    }
    const unsigned int ef = edge_feats_bf[e * 64 + lane];
    ax = fmaf(ax, invd, bf2f(ef & 0xffffu));
    ay = fmaf(ay, invd, bf2f(ef >> 16));
    edge_aggr_bf[e * 64 + lane] = f2bf(ax) | (f2bf(ay) << 16);
}

// ---------------------------------------------------------------------------
// Counting sort of incidences by node id (unordered slot allocation).
__global__ void zero_kernel(int* __restrict__ p, int n)
{
    const int i = blockIdx.x * 256 + threadIdx.x;
    if (i < n) p[i] = 0;
}

__global__ void hist_kernel(const int* __restrict__ nidx, int* __restrict__ cnt)
{
    const int i = blockIdx.x * 256 + threadIdx.x;
    if (i < NINC) atomicAdd(&cnt[nidx[i]], 1);
}

__global__ __launch_bounds__(256) void assign_kernel(
    const int* __restrict__ cnt, int* __restrict__ node_start,
    int* __restrict__ cursor, int* __restrict__ gcursor)
{
    const int n    = blockIdx.x * 256 + threadIdx.x;
    const int lane = threadIdx.x & 63;
    const int c = (n < NNODES) ? cnt[n] : 0;
    int incl = c;
#pragma unroll
    for (int d = 1; d < 64; d <<= 1) {
        const int v = __shfl_up(incl, d);
        if (lane >= d) incl += v;
    }
    const int total = __shfl(incl, 63);
    int base = 0;
    if (lane == 63) base = atomicAdd(gcursor, total);
    base = __shfl(base, 63);
    const int excl = incl - c;
    if (n < NNODES) {
        node_start[n] = base + excl;
        cursor[n]     = base + excl;
    }
}

// K6d: scatter edge id + normalized alpha into node-sorted order.
// Reads are coalesced here (i sequential, eidx sorted); e2n then reads these
// sequentially -- no random small reads left in e2n.
__global__ void nsort_kernel(const int* __restrict__ nidx, const int* __restrict__ eidx,
                             const float* __restrict__ ex, const float* __restrict__ inv_denom,
                             int* __restrict__ cursor, int* __restrict__ sorted_e,
                             float* __restrict__ alpha_ns)
{
    const int i = blockIdx.x * 256 + threadIdx.x;
    if (i >= NINC) return;
    const int n = nidx[i], e = eidx[i];
    const float4 x4 = ((const float4*)ex)[i];
    const float4 d4 = ((const float4*)inv_denom)[e];
    const int pos = atomicAdd(&cursor[n], 1);
    sorted_e[pos] = e;
    ((float4*)alpha_ns)[pos] = make_float4(x4.x * d4.x, x4.y * d4.y, x4.z * d4.z, x4.w * d4.w);
}

// ---------------------------------------------------------------------------
// K7: edge->node gather. One wave per node, 2 bf16 cols per lane.
__global__ __launch_bounds__(256) void e2n_gather_kernel(
    const int* __restrict__ sorted_e, const int* __restrict__ node_start,
    const int* __restrict__ cnt, const float* __restrict__ alpha_ns,
    const unsigned int* __restrict__ edge_aggr_bf,
    const float* __restrict__ bias, float* __restrict__ out)
{
    const int n    = (blockIdx.x * 256 + threadIdx.x) >> 6;
    const int lane = threadIdx.x & 63;
    if (n >= NNODES) return;
    const int s = node_start[n], t = s + cnt[n];
    const int h = lane >> 4;
    float ax = 0.f, ay = 0.f;
    for (int j = s; j < t; ++j) {
        const int e = sorted_e[j];
        const float a = alpha_ns[j * 4 + h];
        const unsigned int v = edge_aggr_bf[e * 64 + lane];
        ax = fmaf(bf2f(v & 0xffffu), a, ax);
        ay = fmaf(bf2f(v >> 16), a, ay);
    }
    const float2 b = ((const float2*)bias)[lane];
    ((float2*)out)[n * 64 + lane] = make_float2(ax + b.x, ay + b.y);
}

// ---------------------------------------------------------------------------
extern "C" void kernel_launch(void* const* d_in, const int* in_sizes, int n_in,
                              void* d_out, int out_size, void* d_ws, size_t ws_size,
                              hipStream_t stream)
{
    const float* x      = (const float*)d_in[0];
    const float* he     = (const float*)d_in[1];
    const int*   nidx   = (const int*)d_in[2];
    const int*   eidx   = (const int*)d_in[3];
    const float* Wn     = (const float*)d_in[4];
    const float* We     = (const float*)d_in[5];
    const float* attn_l = (const float*)d_in[6];
    const float* attn_r = (const float*)d_in[7];
    const float* bias   = (const float*)d_in[8];
    float* out = (float*)d_out;

    char* ws = (char*)d_ws;
    ushort* node_feats = (ushort*)ws;  ws += (size_t)NNODES * 128 * 2;
    ushort* edge_feats = (ushort*)ws;  ws += (size_t)NEDGES * 128 * 2;
    float* alpha_l     = (float*)ws;   ws += (size_t)NNODES * 4 * 4;
    float* alpha_r     = (float*)ws;   ws += (size_t)NEDGES * 4 * 4;
    float* ex          = (float*)ws;   ws += (size_t)NINC * 4 * 4;
    float* inv_denom   = (float*)ws;   ws += (size_t)NEDGES * 4 * 4;
    unsigned int* edge_aggr = (unsigned int*)ws; ws += (size_t)NEDGES * 64 * 4;
    int*   edge_start  = (int*)ws;     ws += (size_t)(NEDGES + 4) * 4;
    int*   cnt         = (int*)ws;     ws += (size_t)(NNODES + 4) * 4;  // +gcursor
    int*   node_start  = (int*)ws;     ws += (size_t)(NNODES + 4) * 4;
    int*   cursor      = (int*)ws;     ws += (size_t)NNODES * 4;
    int*   sorted_e    = (int*)ws;     ws += (size_t)NINC * 4;
    float* alpha_ns    = (float*)ws;   ws += (size_t)NINC * 4 * 4;
    int*   gcursor     = cnt + NNODES;

    // projections + attention scores (bf16 feature tables)
    proj_kernel<<<(NNODES + 31) / 32, 256, 0, stream>>>(x, Wn, attn_l, node_feats, alpha_l, NNODES);
    proj_kernel<<<(NEDGES + 31) / 32, 256, 0, stream>>>(he, We, attn_r, edge_feats, alpha_r, NEDGES);
    // edge CSR (sorted input)
    csr_kernel<<<(NINC + 255) / 256, 256, 0, stream>>>(eidx, edge_start);
    // node counting-sort bookkeeping
    zero_kernel<<<(NNODES + 1 + 255) / 256, 256, 0, stream>>>(cnt, NNODES + 1);
    hist_kernel<<<(NINC + 255) / 256, 256, 0, stream>>>(nidx, cnt);
    assign_kernel<<<(NNODES + 255) / 256, 256, 0, stream>>>(cnt, node_start, cursor, gcursor);
    // segment softmax (ex + inv_denom)
    softmax_kernel<<<(NEDGES * 64 + 255) / 256, 256, 0, stream>>>(nidx, edge_start, alpha_l, alpha_r, ex, inv_denom);
    // scatter edge ids + normalized alpha into node order
    nsort_kernel<<<(NINC + 255) / 256, 256, 0, stream>>>(nidx, eidx, ex, inv_denom, cursor, sorted_e, alpha_ns);
    // node->edge aggregation (bf16 out)
    n2e_kernel<<<(NEDGES * 64 + 255) / 256, 256, 0, stream>>>(nidx, edge_start, (const unsigned int*)node_feats,
                                                              (const unsigned int*)edge_feats, ex, inv_denom, edge_aggr);
    // edge->node gather
    e2n_gather_kernel<<<(NNODES * 64 + 255) / 256, 256, 0, stream>>>(sorted_e, node_start, cnt, alpha_ns, edge_aggr, bias, out);
}

// Round 5
// 268.534 us; speedup vs baseline: 5.7628x; 1.4146x over previous
//
#include <hip/hip_runtime.h>
#include <hip/hip_bf16.h>
#include <float.h>

#define NNODES 100000
#define NEDGES 25000
#define NINC   800000
#define NH     4

// bf16 <-> f32 helpers (RNE pack, shift unpack)
__device__ __forceinline__ float bf2f(unsigned int u16)
{
    union { unsigned int u; float f; } c;
    c.u = u16 << 16;
    return c.f;
}
__device__ __forceinline__ unsigned int f2bf(float f)
{
    union { float f; unsigned int u; } c;
    c.f = f;
    return (c.u + 0x7FFFu + ((c.u >> 16) & 1u)) >> 16;
}

// component h of lane j's float4 (4 shfls + select; pure-register broadcast)
__device__ __forceinline__ float shfl_sel(const float4& a, int h, int j)
{
    const float c0 = __shfl(a.x, j);
    const float c1 = __shfl(a.y, j);
    const float c2 = __shfl(a.z, j);
    const float c3 = __shfl(a.w, j);
    return (h == 0) ? c0 : (h == 1) ? c1 : (h == 2) ? c2 : c3;
}

// ---------------------------------------------------------------------------
// K1/K2: projection GEMM  feats[rows,128] = X[rows,128] @ W[128,128]  (bf16 out)
//        + fused attention score alpha[rows,4]
__global__ __launch_bounds__(256, 2) void proj_kernel(
    const float* __restrict__ X, const float* __restrict__ W,
    const float* __restrict__ attn, ushort* __restrict__ feats_bf,
    float* __restrict__ alphav, int nrows)
{
    __shared__ float sW[128 * 128];
    __shared__ float sXT[128 * 32];
    const int tid = threadIdx.x;

    {
        const float4* Wg = (const float4*)W;
        float4* sW4 = (float4*)sW;
#pragma unroll
        for (int j = 0; j < 16; ++j) sW4[tid + 256 * j] = Wg[tid + 256 * j];
    }
    const int row0 = blockIdx.x * 32;
    {
        const int r = tid >> 3, kc = tid & 7;
        const int grow = row0 + r;
#pragma unroll
        for (int j = 0; j < 4; ++j) {
            const int k4 = kc + 8 * j;
            float4 v = make_float4(0.f, 0.f, 0.f, 0.f);
            if (grow < nrows) v = ((const float4*)X)[grow * 32 + k4];
            sXT[(4 * k4 + 0) * 32 + r] = v.x;
            sXT[(4 * k4 + 1) * 32 + r] = v.y;
            sXT[(4 * k4 + 2) * 32 + r] = v.z;
            sXT[(4 * k4 + 3) * 32 + r] = v.w;
        }
    }
    __syncthreads();

    const int c  = tid & 31;
    const int rg = tid >> 5;
    float acc[4][4] = {};
#pragma unroll 4
    for (int k = 0; k < 128; ++k) {
        const float4 xv = *(const float4*)&sXT[k * 32 + 4 * rg];
        const float4 wv = *(const float4*)&sW[k * 128 + 4 * c];
        const float xr[4] = {xv.x, xv.y, xv.z, xv.w};
        const float wr[4] = {wv.x, wv.y, wv.z, wv.w};
#pragma unroll
        for (int a = 0; a < 4; ++a)
#pragma unroll
            for (int b = 0; b < 4; ++b)
                acc[a][b] = fmaf(xr[a], wr[b], acc[a][b]);
    }

#pragma unroll
    for (int rr = 0; rr < 4; ++rr) {
        const int grow = row0 + 4 * rg + rr;
        if (grow < nrows) {
            ushort4 o;
            o.x = (ushort)f2bf(acc[rr][0]);
            o.y = (ushort)f2bf(acc[rr][1]);
            o.z = (ushort)f2bf(acc[rr][2]);
            o.w = (ushort)f2bf(acc[rr][3]);
            ((ushort4*)feats_bf)[grow * 32 + c] = o;
        }
    }

    const int h  = c >> 3;
    const int cc = (4 * c) & 31;
    const float a0 = attn[h * 32 + cc + 0];
    const float a1 = attn[h * 32 + cc + 1];
    const float a2 = attn[h * 32 + cc + 2];
    const float a3 = attn[h * 32 + cc + 3];
#pragma unroll
    for (int rr = 0; rr < 4; ++rr) {
        float p = acc[rr][0] * a0 + acc[rr][1] * a1 + acc[rr][2] * a2 + acc[rr][3] * a3;
        p += __shfl_xor(p, 1);
        p += __shfl_xor(p, 2);
        p += __shfl_xor(p, 4);
        if ((c & 7) == 0) {
            const int grow = row0 + 4 * rg + rr;
            if (grow < nrows) alphav[grow * 4 + h] = p;
        }
    }
}

// ---------------------------------------------------------------------------
// K3: edge CSR from sorted edge_idx.
__global__ void csr_kernel(const int* __restrict__ eidx, int* __restrict__ edge_start)
{
    const int i = blockIdx.x * 256 + threadIdx.x;
    if (i >= NINC) return;
    const int cur  = eidx[i];
    const int prev = (i == 0) ? -1 : eidx[i - 1];
    for (int e = prev + 1; e <= cur; ++e) edge_start[e] = i;
    if (i == NINC - 1)
        for (int e = cur + 1; e <= NEDGES; ++e) edge_start[e] = NINC;
}

// ---------------------------------------------------------------------------
// Counting-sort bookkeeping for the node side.
__global__ void zero_kernel(int* __restrict__ p, int n)
{
    const int i = blockIdx.x * 256 + threadIdx.x;
    if (i < n) p[i] = 0;
}

__global__ void hist_kernel(const int* __restrict__ nidx, int* __restrict__ cnt)
{
    const int i = blockIdx.x * 256 + threadIdx.x;
    if (i < NINC) atomicAdd(&cnt[nidx[i]], 1);
}

__global__ __launch_bounds__(256) void assign_kernel(
    const int* __restrict__ cnt, int* __restrict__ node_start,
    int* __restrict__ cursor, int* __restrict__ gcursor)
{
    const int n    = blockIdx.x * 256 + threadIdx.x;
    const int lane = threadIdx.x & 63;
    const int c = (n < NNODES) ? cnt[n] : 0;
    int incl = c;
#pragma unroll
    for (int d = 1; d < 64; d <<= 1) {
        const int v = __shfl_up(incl, d);
        if (lane >= d) incl += v;
    }
    const int total = __shfl(incl, 63);
    int base = 0;
    if (lane == 63) base = atomicAdd(gcursor, total);
    base = __shfl(base, 63);
    const int excl = incl - c;
    if (n < NNODES) {
        node_start[n] = base + excl;
        cursor[n]     = base + excl;
    }
}

// ---------------------------------------------------------------------------
// n2e accumulation for one 64-incidence chunk held in registers.
// nreg: lane j holds node id of incidence (chunk_base + j); a4: lane j holds
// its normalized alpha float4. Unroll-4 puts 4 gathers in flight.
__device__ __forceinline__ void n2e_chunk(
    int nreg, const float4& a4, int mj, int h, int lane,
    const unsigned int* __restrict__ nf, float& ax, float& ay)
{
    int j = 0;
    for (; j + 4 <= mj; j += 4) {
        const int n0 = __shfl(nreg, j + 0);
        const int n1 = __shfl(nreg, j + 1);
        const int n2 = __shfl(nreg, j + 2);
        const int n3 = __shfl(nreg, j + 3);
        const unsigned int v0 = nf[n0 * 64 + lane];
        const unsigned int v1 = nf[n1 * 64 + lane];
        const unsigned int v2 = nf[n2 * 64 + lane];
        const unsigned int v3 = nf[n3 * 64 + lane];
        const float q0 = shfl_sel(a4, h, j + 0);
        const float q1 = shfl_sel(a4, h, j + 1);
        const float q2 = shfl_sel(a4, h, j + 2);
        const float q3 = shfl_sel(a4, h, j + 3);
        ax = fmaf(bf2f(v0 & 0xffffu), q0, ax); ay = fmaf(bf2f(v0 >> 16), q0, ay);
        ax = fmaf(bf2f(v1 & 0xffffu), q1, ax); ay = fmaf(bf2f(v1 >> 16), q1, ay);
        ax = fmaf(bf2f(v2 & 0xffffu), q2, ax); ay = fmaf(bf2f(v2 >> 16), q2, ay);
        ax = fmaf(bf2f(v3 & 0xffffu), q3, ax); ay = fmaf(bf2f(v3 >> 16), q3, ay);
    }
    for (; j < mj; ++j) {
        const int nn = __shfl(nreg, j);
        const unsigned int v = nf[nn * 64 + lane];
        const float q = shfl_sel(a4, h, j);
        ax = fmaf(bf2f(v & 0xffffu), q, ax); ay = fmaf(bf2f(v >> 16), q, ay);
    }
}

// ---------------------------------------------------------------------------
// K4: FUSED edge pipeline — one wave per edge:
//   segment softmax (scores cached in regs across passes)
//   + scatter of normalized alpha into node-sorted slots
//   + node->edge aggregation (bf16 out)
__global__ __launch_bounds__(256) void fused_edge_kernel(
    const int* __restrict__ nidx, const int* __restrict__ estart,
    const float* __restrict__ alpha_l, const float* __restrict__ alpha_r,
    const unsigned int* __restrict__ node_feats_bf,
    const unsigned int* __restrict__ edge_feats_bf,
    int* __restrict__ cursor, int* __restrict__ sorted_e,
    float* __restrict__ alpha_s, unsigned int* __restrict__ edge_aggr_bf)
{
    const int e_id = (blockIdx.x * 256 + threadIdx.x) >> 6;
    const int lane = threadIdx.x & 63;
    if (e_id >= NEDGES) return;
    const int s = estart[e_id], t = estart[e_id + 1];
    if (s >= t) return;
    const int deg = t - s;
    const float4 ar = ((const float4*)alpha_r)[e_id];

    // ---- pass 1: scores (chunks 0,1 cached in registers), running max
    int    nc0 = 0, nc1 = 0;
    float4 sc0 = make_float4(0.f, 0.f, 0.f, 0.f), sc1 = sc0;
    float m0 = -FLT_MAX, m1 = -FLT_MAX, m2 = -FLT_MAX, m3 = -FLT_MAX;
    if (s + lane < t) {
        nc0 = nidx[s + lane];
        const float4 al = ((const float4*)alpha_l)[nc0];
        sc0 = make_float4(al.x + ar.x, al.y + ar.y, al.z + ar.z, al.w + ar.w);
        m0 = sc0.x; m1 = sc0.y; m2 = sc0.z; m3 = sc0.w;
    }
    if (deg > 64 && s + 64 + lane < t) {
        nc1 = nidx[s + 64 + lane];
        const float4 al = ((const float4*)alpha_l)[nc1];
        sc1 = make_float4(al.x + ar.x, al.y + ar.y, al.z + ar.z, al.w + ar.w);
        m0 = fmaxf(m0, sc1.x); m1 = fmaxf(m1, sc1.y);
        m2 = fmaxf(m2, sc1.z); m3 = fmaxf(m3, sc1.w);
    }
    for (int c = 2; c * 64 < deg; ++c) {  // cold path (deg > 128)
        const int i = s + c * 64 + lane;
        if (i < t) {
            const float4 al = ((const float4*)alpha_l)[nidx[i]];
            m0 = fmaxf(m0, al.x + ar.x); m1 = fmaxf(m1, al.y + ar.y);
            m2 = fmaxf(m2, al.z + ar.z); m3 = fmaxf(m3, al.w + ar.w);
        }
    }
#pragma unroll
    for (int d = 1; d < 64; d <<= 1) {
        m0 = fmaxf(m0, __shfl_xor(m0, d));
        m1 = fmaxf(m1, __shfl_xor(m1, d));
        m2 = fmaxf(m2, __shfl_xor(m2, d));
        m3 = fmaxf(m3, __shfl_xor(m3, d));
    }

    // ---- pass 2: exp + sum (exp overwrites cached scores)
    float s0 = 0.f, s1 = 0.f, s2 = 0.f, s3 = 0.f;
    if (s + lane < t) {
        sc0.x = __expf(sc0.x - m0); sc0.y = __expf(sc0.y - m1);
        sc0.z = __expf(sc0.z - m2); sc0.w = __expf(sc0.w - m3);
        s0 += sc0.x; s1 += sc0.y; s2 += sc0.z; s3 += sc0.w;
    }
    if (deg > 64 && s + 64 + lane < t) {
        sc1.x = __expf(sc1.x - m0); sc1.y = __expf(sc1.y - m1);
        sc1.z = __expf(sc1.z - m2); sc1.w = __expf(sc1.w - m3);
        s0 += sc1.x; s1 += sc1.y; s2 += sc1.z; s3 += sc1.w;
    }
    for (int c = 2; c * 64 < deg; ++c) {
        const int i = s + c * 64 + lane;
        if (i < t) {
            const float4 al = ((const float4*)alpha_l)[nidx[i]];
            s0 += __expf(al.x + ar.x - m0); s1 += __expf(al.y + ar.y - m1);
            s2 += __expf(al.z + ar.z - m2); s3 += __expf(al.w + ar.w - m3);
        }
    }
#pragma unroll
    for (int d = 1; d < 64; d <<= 1) {
        s0 += __shfl_xor(s0, d); s1 += __shfl_xor(s1, d);
        s2 += __shfl_xor(s2, d); s3 += __shfl_xor(s3, d);
    }
    const float i0 = 1.f / s0, i1 = 1.f / s1, i2 = 1.f / s2, i3 = 1.f / s3;

    // ---- pass 3: scatter normalized alpha + n2e accumulation
    float ax = 0.f, ay = 0.f;
    const int h = lane >> 4;
    {
        const float4 a4 = make_float4(sc0.x * i0, sc0.y * i1, sc0.z * i2, sc0.w * i3);
        if (s + lane < t) {
            const int pos = atomicAdd(&cursor[nc0], 1);
            sorted_e[pos] = e_id;
            ((float4*)alpha_s)[pos] = a4;
        }
        n2e_chunk(nc0, a4, min(64, deg), h, lane, node_feats_bf, ax, ay);
    }
    if (deg > 64) {
        const float4 a4 = make_float4(sc1.x * i0, sc1.y * i1, sc1.z * i2, sc1.w * i3);
        if (s + 64 + lane < t) {
            const int pos = atomicAdd(&cursor[nc1], 1);
            sorted_e[pos] = e_id;
            ((float4*)alpha_s)[pos] = a4;
        }
        n2e_chunk(nc1, a4, min(64, deg - 64), h, lane, node_feats_bf, ax, ay);
    }
    for (int c = 2; c * 64 < deg; ++c) {  // cold path (deg > 128)
        const int i = s + c * 64 + lane;
        int nn = 0;
        float4 a4 = make_float4(0.f, 0.f, 0.f, 0.f);
        if (i < t) {
            nn = nidx[i];
            const float4 al = ((const float4*)alpha_l)[nn];
            a4.x = __expf(al.x + ar.x - m0) * i0; a4.y = __expf(al.y + ar.y - m1) * i1;
            a4.z = __expf(al.z + ar.z - m2) * i2; a4.w = __expf(al.w + ar.w - m3) * i3;
            const int pos = atomicAdd(&cursor[nn], 1);
            sorted_e[pos] = e_id;
            ((float4*)alpha_s)[pos] = a4;
        }
        n2e_chunk(nn, a4, min(64, deg - c * 64), h, lane, node_feats_bf, ax, ay);
    }

    const unsigned int ef = edge_feats_bf[e_id * 64 + lane];
    ax += bf2f(ef & 0xffffu);
    ay += bf2f(ef >> 16);
    edge_aggr_bf[e_id * 64 + lane] = f2bf(ax) | (f2bf(ay) << 16);
}

// ---------------------------------------------------------------------------
// K5: edge->node gather with prefetch-and-broadcast + unroll-4.
__global__ __launch_bounds__(256) void e2n_gather_kernel(
    const int* __restrict__ sorted_e, const int* __restrict__ node_start,
    const int* __restrict__ cnt, const float* __restrict__ alpha_s,
    const unsigned int* __restrict__ edge_aggr_bf,
    const float* __restrict__ bias, float* __restrict__ out)
{
    const int n    = (blockIdx.x * 256 + threadIdx.x) >> 6;
    const int lane = threadIdx.x & 63;
    if (n >= NNODES) return;
    const int s   = node_start[n];
    const int deg = cnt[n];
    const int h = lane >> 4;
    float ax = 0.f, ay = 0.f;
    for (int base = 0; base < deg; base += 64) {
        const int mj = min(64, deg - base);
        int ej = 0;
        float4 a4 = make_float4(0.f, 0.f, 0.f, 0.f);
        if (lane < mj) {
            ej = sorted_e[s + base + lane];
            a4 = ((const float4*)alpha_s)[s + base + lane];
        }
        int j = 0;
        for (; j + 4 <= mj; j += 4) {
            const int e0 = __shfl(ej, j + 0);
            const int e1 = __shfl(ej, j + 1);
            const int e2 = __shfl(ej, j + 2);
            const int e3 = __shfl(ej, j + 3);
            const unsigned int v0 = edge_aggr_bf[e0 * 64 + lane];
            const unsigned int v1 = edge_aggr_bf[e1 * 64 + lane];
            const unsigned int v2 = edge_aggr_bf[e2 * 64 + lane];
            const unsigned int v3 = edge_aggr_bf[e3 * 64 + lane];
            const float q0 = shfl_sel(a4, h, j + 0);
            const float q1 = shfl_sel(a4, h, j + 1);
            const float q2 = shfl_sel(a4, h, j + 2);
            const float q3 = shfl_sel(a4, h, j + 3);
            ax = fmaf(bf2f(v0 & 0xffffu), q0, ax); ay = fmaf(bf2f(v0 >> 16), q0, ay);
            ax = fmaf(bf2f(v1 & 0xffffu), q1, ax); ay = fmaf(bf2f(v1 >> 16), q1, ay);
            ax = fmaf(bf2f(v2 & 0xffffu), q2, ax); ay = fmaf(bf2f(v2 >> 16), q2, ay);
            ax = fmaf(bf2f(v3 & 0xffffu), q3, ax); ay = fmaf(bf2f(v3 >> 16), q3, ay);
        }
        for (; j < mj; ++j) {
            const int e = __shfl(ej, j);
            const unsigned int v = edge_aggr_bf[e * 64 + lane];
            const float q = shfl_sel(a4, h, j);
            ax = fmaf(bf2f(v & 0xffffu), q, ax); ay = fmaf(bf2f(v >> 16), q, ay);
        }
    }
    const float2 b = ((const float2*)bias)[lane];
    ((float2*)out)[n * 64 + lane] = make_float2(ax + b.x, ay + b.y);
}

// ---------------------------------------------------------------------------
extern "C" void kernel_launch(void* const* d_in, const int* in_sizes, int n_in,
                              void* d_out, int out_size, void* d_ws, size_t ws_size,
                              hipStream_t stream)
{
    const float* x      = (const float*)d_in[0];
    const float* he     = (const float*)d_in[1];
    const int*   nidx   = (const int*)d_in[2];
    const int*   eidx   = (const int*)d_in[3];
    const float* Wn     = (const float*)d_in[4];
    const float* We     = (const float*)d_in[5];
    const float* attn_l = (const float*)d_in[6];
    const float* attn_r = (const float*)d_in[7];
    const float* bias   = (const float*)d_in[8];
    float* out = (float*)d_out;

    char* ws = (char*)d_ws;
    ushort* node_feats = (ushort*)ws;  ws += (size_t)NNODES * 128 * 2;
    ushort* edge_feats = (ushort*)ws;  ws += (size_t)NEDGES * 128 * 2;
    float* alpha_l     = (float*)ws;   ws += (size_t)NNODES * 4 * 4;
    float* alpha_r     = (float*)ws;   ws += (size_t)NEDGES * 4 * 4;
    unsigned int* edge_aggr = (unsigned int*)ws; ws += (size_t)NEDGES * 64 * 4;
    int*   edge_start  = (int*)ws;     ws += (size_t)(NEDGES + 4) * 4;
    int*   cnt         = (int*)ws;     ws += (size_t)(NNODES + 4) * 4;  // +gcursor
    int*   node_start  = (int*)ws;     ws += (size_t)(NNODES + 4) * 4;
    int*   cursor      = (int*)ws;     ws += (size_t)NNODES * 4;
    int*   sorted_e    = (int*)ws;     ws += (size_t)NINC * 4;
    float* alpha_s     = (float*)ws;   ws += (size_t)NINC * 4 * 4;
    int*   gcursor     = cnt + NNODES;

    // projections + attention scores (bf16 feature tables)
    proj_kernel<<<(NNODES + 31) / 32, 256, 0, stream>>>(x, Wn, attn_l, node_feats, alpha_l, NNODES);
    proj_kernel<<<(NEDGES + 31) / 32, 256, 0, stream>>>(he, We, attn_r, edge_feats, alpha_r, NEDGES);
    // edge CSR (sorted input)
    csr_kernel<<<(NINC + 255) / 256, 256, 0, stream>>>(eidx, edge_start);
    // node counting-sort bookkeeping
    zero_kernel<<<(NNODES + 1 + 255) / 256, 256, 0, stream>>>(cnt, NNODES + 1);
    hist_kernel<<<(NINC + 255) / 256, 256, 0, stream>>>(nidx, cnt);
    assign_kernel<<<(NNODES + 255) / 256, 256, 0, stream>>>(cnt, node_start, cursor, gcursor);
    // fused: softmax + alpha scatter + node->edge aggregation
    fused_edge_kernel<<<(NEDGES * 64 + 255) / 256, 256, 0, stream>>>(
        nidx, edge_start, alpha_l, alpha_r, (const unsigned int*)node_feats,
        (const unsigned int*)edge_feats, cursor, sorted_e, alpha_s, edge_aggr);
    // edge->node gather
    e2n_gather_kernel<<<(NNODES * 64 + 255) / 256, 256, 0, stream>>>(
        sorted_e, node_start, cnt, alpha_s, edge_aggr, bias, out);
}

// Round 6
// 242.508 us; speedup vs baseline: 6.3813x; 1.1073x over previous
//
#include <hip/hip_runtime.h>
#include <hip/hip_bf16.h>
#include <float.h>

#define NNODES 100000
#define NEDGES 25000
#define NINC   800000
#define NH     4

typedef short bf16x8 __attribute__((ext_vector_type(8)));
typedef float f32x4  __attribute__((ext_vector_type(4)));

// bf16 <-> f32 helpers (RNE pack, shift unpack)
__device__ __forceinline__ float bf2f(unsigned int u16)
{
    union { unsigned int u; float f; } c;
    c.u = u16 << 16;
    return c.f;
}
__device__ __forceinline__ unsigned int f2bf(float f)
{
    union { float f; unsigned int u; } c;
    c.f = f;
    return (c.u + 0x7FFFu + ((c.u >> 16) & 1u)) >> 16;
}

// component h of lane j's float4 (4 shfls + select; pure-register broadcast)
__device__ __forceinline__ float shfl_sel(const float4& a, int h, int j)
{
    const float c0 = __shfl(a.x, j);
    const float c1 = __shfl(a.y, j);
    const float c2 = __shfl(a.z, j);
    const float c3 = __shfl(a.w, j);
    return (h == 0) ? c0 : (h == 1) ? c1 : (h == 2) ? c2 : c3;
}

// ---------------------------------------------------------------------------
// K1/K2: MFMA projection. feats[rows,128] = bf16(X[rows,128] @ W[128,128])
// + fused attention score alpha[rows,4].
// Block = 256 thr (4 waves), 64 rows. LDS: X-tile 16KB + W^T 32KB, both bf16
// with XOR slot-swizzle (slot ^= row&7) -> 2-way (free) ds_read_b128.
// MFMA 16x16x32_bf16; C/D mapping col=lane&15, row=(lane>>4)*4+reg.
__global__ __launch_bounds__(256, 3) void proj_mfma_kernel(
    const float* __restrict__ X, const float* __restrict__ W,
    const float* __restrict__ attn, ushort* __restrict__ feats_bf,
    float* __restrict__ alphav, int nrows)
{
    __shared__ uint4  sX[64 * 16];     // [row][slot] bf16x8 slots, swizzled
    __shared__ ushort sWT[128 * 128];  // [n][k] bf16, swizzled per 8-bf16 slot
    const int tid  = threadIdx.x;
    const int row0 = blockIdx.x * 64;

    // stage X -> bf16 LDS (coalesced float4 reads)
#pragma unroll
    for (int it = 0; it < 4; ++it) {
        const int si = tid + 256 * it;         // 0..1023
        const int r = si >> 4, slot = si & 15;
        const int grow = row0 + r;
        float4 v0 = make_float4(0.f, 0.f, 0.f, 0.f), v1 = v0;
        if (grow < nrows) {
            v0 = ((const float4*)X)[grow * 32 + slot * 2];
            v1 = ((const float4*)X)[grow * 32 + slot * 2 + 1];
        }
        uint4 p;
        p.x = f2bf(v0.x) | (f2bf(v0.y) << 16);
        p.y = f2bf(v0.z) | (f2bf(v0.w) << 16);
        p.z = f2bf(v1.x) | (f2bf(v1.y) << 16);
        p.w = f2bf(v1.z) | (f2bf(v1.w) << 16);
        sX[r * 16 + (slot ^ (r & 7))] = p;
    }
    // stage W^T -> bf16 LDS (coalesced read, scattered 2B LDS writes; one-time)
#pragma unroll
    for (int it = 0; it < 16; ++it) {
        const int f = tid + 256 * it;          // 0..4095
        const int k = f >> 5, n0 = (f & 31) * 4;
        const float4 wv = ((const float4*)W)[f];
        const float wa[4] = {wv.x, wv.y, wv.z, wv.w};
#pragma unroll
        for (int i2 = 0; i2 < 4; ++i2) {
            const int n = n0 + i2;
            sWT[n * 128 + (((k >> 3) ^ (n & 7)) * 8) + (k & 7)] = (ushort)f2bf(wa[i2]);
        }
    }
    __syncthreads();

    const int w = tid >> 6, lane = tid & 63;
    const int m = lane & 15, kq = lane >> 4;
    f32x4 acc[8];
#pragma unroll
    for (int ct = 0; ct < 8; ++ct) acc[ct] = (f32x4)0.f;

    const int r = w * 16 + m;  // r&7 == m&7
#pragma unroll
    for (int ks = 0; ks < 4; ++ks) {
        const bf16x8 a = *(const bf16x8*)&sX[r * 16 + ((kq + 4 * ks) ^ (m & 7))];
#pragma unroll
        for (int ct = 0; ct < 8; ++ct) {
            const int n = ct * 16 + m;  // n&7 == m&7
            const bf16x8 b = *(const bf16x8*)&sWT[n * 128 + (((kq + 4 * ks) ^ (m & 7)) * 8)];
            acc[ct] = __builtin_amdgcn_mfma_f32_16x16x32_bf16(a, b, acc[ct], 0, 0, 0);
        }
    }

    // attn weights needed by this lane: attn[h][m] and attn[h][16+m]
    float att[8];
#pragma unroll
    for (int h = 0; h < 4; ++h) {
        att[2 * h]     = attn[h * 32 + m];
        att[2 * h + 1] = attn[h * 32 + 16 + m];
    }
#pragma unroll
    for (int reg = 0; reg < 4; ++reg) {
        const int grow = row0 + w * 16 + kq * 4 + reg;
        const bool ok = grow < nrows;
        float p0 = acc[0][reg] * att[0] + acc[1][reg] * att[1];
        float p1 = acc[2][reg] * att[2] + acc[3][reg] * att[3];
        float p2 = acc[4][reg] * att[4] + acc[5][reg] * att[5];
        float p3 = acc[6][reg] * att[6] + acc[7][reg] * att[7];
#pragma unroll
        for (int d = 1; d < 16; d <<= 1) {
            p0 += __shfl_xor(p0, d);
            p1 += __shfl_xor(p1, d);
            p2 += __shfl_xor(p2, d);
            p3 += __shfl_xor(p3, d);
        }
        if (ok) {
#pragma unroll
            for (int ct = 0; ct < 8; ++ct)
                feats_bf[grow * 128 + ct * 16 + m] = (ushort)f2bf(acc[ct][reg]);
            if (m == 0)
                ((float4*)alphav)[grow] = make_float4(p0, p1, p2, p3);
        }
    }
}

// ---------------------------------------------------------------------------
// K3: edge CSR from sorted edge_idx.
__global__ void csr_kernel(const int* __restrict__ eidx, int* __restrict__ edge_start)
{
    const int i = blockIdx.x * 256 + threadIdx.x;
    if (i >= NINC) return;
    const int cur  = eidx[i];
    const int prev = (i == 0) ? -1 : eidx[i - 1];
    for (int e = prev + 1; e <= cur; ++e) edge_start[e] = i;
    if (i == NINC - 1)
        for (int e = cur + 1; e <= NEDGES; ++e) edge_start[e] = NINC;
}

// ---------------------------------------------------------------------------
// Counting-sort bookkeeping for the node side.
__global__ void zero_kernel(int* __restrict__ p, int n)
{
    const int i = blockIdx.x * 256 + threadIdx.x;
    if (i < n) p[i] = 0;
}

__global__ void hist_kernel(const int* __restrict__ nidx, int* __restrict__ cnt)
{
    const int i = blockIdx.x * 256 + threadIdx.x;
    if (i < NINC) atomicAdd(&cnt[nidx[i]], 1);
}

__global__ __launch_bounds__(256) void assign_kernel(
    const int* __restrict__ cnt, int* __restrict__ node_start,
    int* __restrict__ cursor, int* __restrict__ gcursor)
{
    const int n    = blockIdx.x * 256 + threadIdx.x;
    const int lane = threadIdx.x & 63;
    const int c = (n < NNODES) ? cnt[n] : 0;
    int incl = c;
#pragma unroll
    for (int d = 1; d < 64; d <<= 1) {
        const int v = __shfl_up(incl, d);
        if (lane >= d) incl += v;
    }
    const int total = __shfl(incl, 63);
    int base = 0;
    if (lane == 63) base = atomicAdd(gcursor, total);
    base = __shfl(base, 63);
    const int excl = incl - c;
    if (n < NNODES) {
        node_start[n] = base + excl;
        cursor[n]     = base + excl;
    }
}

// ---------------------------------------------------------------------------
// n2e accumulation for one 64-incidence chunk held in registers. Unroll-8.
__device__ __forceinline__ void n2e_chunk(
    int nreg, const float4& a4, int mj, int h, int lane,
    const unsigned int* __restrict__ nf, float& ax, float& ay)
{
    int j = 0;
    for (; j + 8 <= mj; j += 8) {
        int nn[8]; unsigned int v[8]; float q[8];
#pragma unroll
        for (int u = 0; u < 8; ++u) nn[u] = __shfl(nreg, j + u);
#pragma unroll
        for (int u = 0; u < 8; ++u) v[u] = nf[nn[u] * 64 + lane];
#pragma unroll
        for (int u = 0; u < 8; ++u) q[u] = shfl_sel(a4, h, j + u);
#pragma unroll
        for (int u = 0; u < 8; ++u) {
            ax = fmaf(bf2f(v[u] & 0xffffu), q[u], ax);
            ay = fmaf(bf2f(v[u] >> 16), q[u], ay);
        }
    }
    for (; j < mj; ++j) {
        const int nn = __shfl(nreg, j);
        const unsigned int v = nf[nn * 64 + lane];
        const float q = shfl_sel(a4, h, j);
        ax = fmaf(bf2f(v & 0xffffu), q, ax); ay = fmaf(bf2f(v >> 16), q, ay);
    }
}

// ---------------------------------------------------------------------------
// K4: FUSED edge pipeline — one wave per edge:
//   segment softmax (scores cached in regs) + scatter of normalized alpha
//   into node-sorted slots + node->edge aggregation (bf16 out)
__global__ __launch_bounds__(256) void fused_edge_kernel(
    const int* __restrict__ nidx, const int* __restrict__ estart,
    const float* __restrict__ alpha_l, const float* __restrict__ alpha_r,
    const unsigned int* __restrict__ node_feats_bf,
    const unsigned int* __restrict__ edge_feats_bf,
    int* __restrict__ cursor, int* __restrict__ sorted_e,
    float* __restrict__ alpha_s, unsigned int* __restrict__ edge_aggr_bf)
{
    const int e_id = (blockIdx.x * 256 + threadIdx.x) >> 6;
    const int lane = threadIdx.x & 63;
    if (e_id >= NEDGES) return;
    const int s = estart[e_id], t = estart[e_id + 1];
    if (s >= t) return;
    const int deg = t - s;
    const float4 ar = ((const float4*)alpha_r)[e_id];

    // ---- pass 1: scores (chunks 0,1 cached in registers), running max
    int    nc0 = 0, nc1 = 0;
    float4 sc0 = make_float4(0.f, 0.f, 0.f, 0.f), sc1 = sc0;
    float m0 = -FLT_MAX, m1 = -FLT_MAX, m2 = -FLT_MAX, m3 = -FLT_MAX;
    if (s + lane < t) {
        nc0 = nidx[s + lane];
        const float4 al = ((const float4*)alpha_l)[nc0];
        sc0 = make_float4(al.x + ar.x, al.y + ar.y, al.z + ar.z, al.w + ar.w);
        m0 = sc0.x; m1 = sc0.y; m2 = sc0.z; m3 = sc0.w;
    }
    if (deg > 64 && s + 64 + lane < t) {
        nc1 = nidx[s + 64 + lane];
        const float4 al = ((const float4*)alpha_l)[nc1];
        sc1 = make_float4(al.x + ar.x, al.y + ar.y, al.z + ar.z, al.w + ar.w);
        m0 = fmaxf(m0, sc1.x); m1 = fmaxf(m1, sc1.y);
        m2 = fmaxf(m2, sc1.z); m3 = fmaxf(m3, sc1.w);
    }
    for (int c = 2; c * 64 < deg; ++c) {  // cold path (deg > 128)
        const int i = s + c * 64 + lane;
        if (i < t) {
            const float4 al = ((const float4*)alpha_l)[nidx[i]];
            m0 = fmaxf(m0, al.x + ar.x); m1 = fmaxf(m1, al.y + ar.y);
            m2 = fmaxf(m2, al.z + ar.z); m3 = fmaxf(m3, al.w + ar.w);
        }
    }
#pragma unroll
    for (int d = 1; d < 64; d <<= 1) {
        m0 = fmaxf(m0, __shfl_xor(m0, d));
        m1 = fmaxf(m1, __shfl_xor(m1, d));
        m2 = fmaxf(m2, __shfl_xor(m2, d));
        m3 = fmaxf(m3, __shfl_xor(m3, d));
    }

    // ---- pass 2: exp + sum (exp overwrites cached scores)
    float s0 = 0.f, s1 = 0.f, s2 = 0.f, s3 = 0.f;
    if (s + lane < t) {
        sc0.x = __expf(sc0.x - m0); sc0.y = __expf(sc0.y - m1);
        sc0.z = __expf(sc0.z - m2); sc0.w = __expf(sc0.w - m3);
        s0 += sc0.x; s1 += sc0.y; s2 += sc0.z; s3 += sc0.w;
    }
    if (deg > 64 && s + 64 + lane < t) {
        sc1.x = __expf(sc1.x - m0); sc1.y = __expf(sc1.y - m1);
        sc1.z = __expf(sc1.z - m2); sc1.w = __expf(sc1.w - m3);
        s0 += sc1.x; s1 += sc1.y; s2 += sc1.z; s3 += sc1.w;
    }
    for (int c = 2; c * 64 < deg; ++c) {
        const int i = s + c * 64 + lane;
        if (i < t) {
            const float4 al = ((const float4*)alpha_l)[nidx[i]];
            s0 += __expf(al.x + ar.x - m0); s1 += __expf(al.y + ar.y - m1);
            s2 += __expf(al.z + ar.z - m2); s3 += __expf(al.w + ar.w - m3);
        }
    }
#pragma unroll
    for (int d = 1; d < 64; d <<= 1) {
        s0 += __shfl_xor(s0, d); s1 += __shfl_xor(s1, d);
        s2 += __shfl_xor(s2, d); s3 += __shfl_xor(s3, d);
    }
    const float i0 = 1.f / s0, i1 = 1.f / s1, i2 = 1.f / s2, i3 = 1.f / s3;

    // ---- pass 3: scatter normalized alpha + n2e accumulation
    float ax = 0.f, ay = 0.f;
    const int h = lane >> 4;
    {
        const float4 a4 = make_float4(sc0.x * i0, sc0.y * i1, sc0.z * i2, sc0.w * i3);
        if (s + lane < t) {
            const int pos = atomicAdd(&cursor[nc0], 1);
            sorted_e[pos] = e_id;
            ((float4*)alpha_s)[pos] = a4;
        }
        n2e_chunk(nc0, a4, min(64, deg), h, lane, node_feats_bf, ax, ay);
    }
    if (deg > 64) {
        const float4 a4 = make_float4(sc1.x * i0, sc1.y * i1, sc1.z * i2, sc1.w * i3);
        if (s + 64 + lane < t) {
            const int pos = atomicAdd(&cursor[nc1], 1);
            sorted_e[pos] = e_id;
            ((float4*)alpha_s)[pos] = a4;
        }
        n2e_chunk(nc1, a4, min(64, deg - 64), h, lane, node_feats_bf, ax, ay);
    }
    for (int c = 2; c * 64 < deg; ++c) {  // cold path (deg > 128)
        const int i = s + c * 64 + lane;
        int nn = 0;
        float4 a4 = make_float4(0.f, 0.f, 0.f, 0.f);
        if (i < t) {
            nn = nidx[i];
            const float4 al = ((const float4*)alpha_l)[nn];
            a4.x = __expf(al.x + ar.x - m0) * i0; a4.y = __expf(al.y + ar.y - m1) * i1;
            a4.z = __expf(al.z + ar.z - m2) * i2; a4.w = __expf(al.w + ar.w - m3) * i3;
            const int pos = atomicAdd(&cursor[nn], 1);
            sorted_e[pos] = e_id;
            ((float4*)alpha_s)[pos] = a4;
        }
        n2e_chunk(nn, a4, min(64, deg - c * 64), h, lane, node_feats_bf, ax, ay);
    }

    const unsigned int ef = edge_feats_bf[e_id * 64 + lane];
    ax += bf2f(ef & 0xffffu);
    ay += bf2f(ef >> 16);
    edge_aggr_bf[e_id * 64 + lane] = f2bf(ax) | (f2bf(ay) << 16);
}

// ---------------------------------------------------------------------------
// K5: edge->node gather with prefetch-and-broadcast + unroll-8.
__global__ __launch_bounds__(256) void e2n_gather_kernel(
    const int* __restrict__ sorted_e, const int* __restrict__ node_start,
    const int* __restrict__ cnt, const float* __restrict__ alpha_s,
    const unsigned int* __restrict__ edge_aggr_bf,
    const float* __restrict__ bias, float* __restrict__ out)
{
    const int n    = (blockIdx.x * 256 + threadIdx.x) >> 6;
    const int lane = threadIdx.x & 63;
    if (n >= NNODES) return;
    const int s   = node_start[n];
    const int deg = cnt[n];
    const int h = lane >> 4;
    float ax = 0.f, ay = 0.f;
    for (int base = 0; base < deg; base += 64) {
        const int mj = min(64, deg - base);
        int ej = 0;
        float4 a4 = make_float4(0.f, 0.f, 0.f, 0.f);
        if (lane < mj) {
            ej = sorted_e[s + base + lane];
            a4 = ((const float4*)alpha_s)[s + base + lane];
        }
        int j = 0;
        for (; j + 8 <= mj; j += 8) {
            int ee[8]; unsigned int v[8]; float q[8];
#pragma unroll
            for (int u = 0; u < 8; ++u) ee[u] = __shfl(ej, j + u);
#pragma unroll
            for (int u = 0; u < 8; ++u) v[u] = edge_aggr_bf[ee[u] * 64 + lane];
#pragma unroll
            for (int u = 0; u < 8; ++u) q[u] = shfl_sel(a4, h, j + u);
#pragma unroll
            for (int u = 0; u < 8; ++u) {
                ax = fmaf(bf2f(v[u] & 0xffffu), q[u], ax);
                ay = fmaf(bf2f(v[u] >> 16), q[u], ay);
            }
        }
        for (; j < mj; ++j) {
            const int e = __shfl(ej, j);
            const unsigned int v = edge_aggr_bf[e * 64 + lane];
            const float q = shfl_sel(a4, h, j);
            ax = fmaf(bf2f(v & 0xffffu), q, ax); ay = fmaf(bf2f(v >> 16), q, ay);
        }
    }
    const float2 b = ((const float2*)bias)[lane];
    ((float2*)out)[n * 64 + lane] = make_float2(ax + b.x, ay + b.y);
}

// ---------------------------------------------------------------------------
extern "C" void kernel_launch(void* const* d_in, const int* in_sizes, int n_in,
                              void* d_out, int out_size, void* d_ws, size_t ws_size,
                              hipStream_t stream)
{
    const float* x      = (const float*)d_in[0];
    const float* he     = (const float*)d_in[1];
    const int*   nidx   = (const int*)d_in[2];
    const int*   eidx   = (const int*)d_in[3];
    const float* Wn     = (const float*)d_in[4];
    const float* We     = (const float*)d_in[5];
    const float* attn_l = (const float*)d_in[6];
    const float* attn_r = (const float*)d_in[7];
    const float* bias   = (const float*)d_in[8];
    float* out = (float*)d_out;

    char* ws = (char*)d_ws;
    ushort* node_feats = (ushort*)ws;  ws += (size_t)NNODES * 128 * 2;
    ushort* edge_feats = (ushort*)ws;  ws += (size_t)NEDGES * 128 * 2;
    float* alpha_l     = (float*)ws;   ws += (size_t)NNODES * 4 * 4;
    float* alpha_r     = (float*)ws;   ws += (size_t)NEDGES * 4 * 4;
    unsigned int* edge_aggr = (unsigned int*)ws; ws += (size_t)NEDGES * 64 * 4;
    int*   edge_start  = (int*)ws;     ws += (size_t)(NEDGES + 4) * 4;
    int*   cnt         = (int*)ws;     ws += (size_t)(NNODES + 4) * 4;  // +gcursor
    int*   node_start  = (int*)ws;     ws += (size_t)(NNODES + 4) * 4;
    int*   cursor      = (int*)ws;     ws += (size_t)NNODES * 4;
    int*   sorted_e    = (int*)ws;     ws += (size_t)NINC * 4;
    float* alpha_s     = (float*)ws;   ws += (size_t)NINC * 4 * 4;
    int*   gcursor     = cnt + NNODES;

    // projections + attention scores (bf16 feature tables) via MFMA
    proj_mfma_kernel<<<(NNODES + 63) / 64, 256, 0, stream>>>(x, Wn, attn_l, node_feats, alpha_l, NNODES);
    proj_mfma_kernel<<<(NEDGES + 63) / 64, 256, 0, stream>>>(he, We, attn_r, edge_feats, alpha_r, NEDGES);
    // edge CSR (sorted input)
    csr_kernel<<<(NINC + 255) / 256, 256, 0, stream>>>(eidx, edge_start);
    // node counting-sort bookkeeping
    zero_kernel<<<(NNODES + 1 + 255) / 256, 256, 0, stream>>>(cnt, NNODES + 1);
    hist_kernel<<<(NINC + 255) / 256, 256, 0, stream>>>(nidx, cnt);
    assign_kernel<<<(NNODES + 255) / 256, 256, 0, stream>>>(cnt, node_start, cursor, gcursor);
    // fused: softmax + alpha scatter + node->edge aggregation
    fused_edge_kernel<<<(NEDGES * 64 + 255) / 256, 256, 0, stream>>>(
        nidx, edge_start, alpha_l, alpha_r, (const unsigned int*)node_feats,
        (const unsigned int*)edge_feats, cursor, sorted_e, alpha_s, edge_aggr);
    // edge->node gather
    e2n_gather_kernel<<<(NNODES * 64 + 255) / 256, 256, 0, stream>>>(
        sorted_e, node_start, cnt, alpha_s, edge_aggr, bias, out);
}

// Round 7
// 221.339 us; speedup vs baseline: 6.9916x; 1.0956x over previous
//
#include <hip/hip_runtime.h>
#include <hip/hip_bf16.h>
#include <float.h>

#define NNODES 100000
#define NEDGES 25000
#define NINC   800000
#define NH     4

typedef short bf16x8 __attribute__((ext_vector_type(8)));
typedef float f32x4  __attribute__((ext_vector_type(4)));

// bf16 <-> f32 helpers (RNE pack, shift unpack)
__device__ __forceinline__ float bf2f(unsigned int u16)
{
    union { unsigned int u; float f; } c;
    c.u = u16 << 16;
    return c.f;
}
__device__ __forceinline__ unsigned int f2bf(float f)
{
    union { float f; unsigned int u; } c;
    c.f = f;
    return (c.u + 0x7FFFu + ((c.u >> 16) & 1u)) >> 16;
}

// ---------------------------------------------------------------------------
// K0: one-time W -> W^T bf16 with the 8-slot XOR swizzle (both matrices).
// Layout: WT[n*128 + ((slot ^ (n&7))*8) + (k&7)], slot = k>>3.
__global__ void wt_prep_kernel(const float* __restrict__ Wn, const float* __restrict__ We,
                               ushort* __restrict__ WTn, ushort* __restrict__ WTe)
{
    const int gid = blockIdx.x * 256 + threadIdx.x;  // 0..4095
    const float* W = (gid < 2048) ? Wn : We;
    ushort* WT     = (gid < 2048) ? WTn : WTe;
    const int g  = gid & 2047;
    const int n  = g >> 4, kq = g & 15;
    unsigned int pk[8];
#pragma unroll
    for (int u = 0; u < 8; ++u)
        pk[u] = f2bf(W[(kq * 8 + u) * 128 + n]);
    uint4 v;
    v.x = pk[0] | (pk[1] << 16);
    v.y = pk[2] | (pk[3] << 16);
    v.z = pk[4] | (pk[5] << 16);
    v.w = pk[6] | (pk[7] << 16);
    *(uint4*)&WT[n * 128 + ((kq ^ (n & 7)) * 8)] = v;
}

// ---------------------------------------------------------------------------
// K1/K2: MFMA projection. feats[rows,128] = bf16(X[rows,128] @ W[128,128])
// + fused attention score alpha[rows,4]. W^T comes pre-swizzled (wt_prep).
__global__ __launch_bounds__(256, 3) void proj_mfma_kernel(
    const float* __restrict__ X, const ushort* __restrict__ WT,
    const float* __restrict__ attn, ushort* __restrict__ feats_bf,
    float* __restrict__ alphav, int nrows)
{
    __shared__ uint4  sX[64 * 16];     // [row][slot] bf16x8 slots, swizzled
    __shared__ ushort sWT[128 * 128];  // pre-swizzled copy of WT
    const int tid  = threadIdx.x;
    const int row0 = blockIdx.x * 64;

    // stage X -> bf16 LDS (coalesced float4 reads)
#pragma unroll
    for (int it = 0; it < 4; ++it) {
        const int si = tid + 256 * it;         // 0..1023
        const int r = si >> 4, slot = si & 15;
        const int grow = row0 + r;
        float4 v0 = make_float4(0.f, 0.f, 0.f, 0.f), v1 = v0;
        if (grow < nrows) {
            v0 = ((const float4*)X)[grow * 32 + slot * 2];
            v1 = ((const float4*)X)[grow * 32 + slot * 2 + 1];
        }
        uint4 p;
        p.x = f2bf(v0.x) | (f2bf(v0.y) << 16);
        p.y = f2bf(v0.z) | (f2bf(v0.w) << 16);
        p.z = f2bf(v1.x) | (f2bf(v1.y) << 16);
        p.w = f2bf(v1.z) | (f2bf(v1.w) << 16);
        sX[r * 16 + (slot ^ (r & 7))] = p;
    }
    // stage pre-swizzled W^T (clean coalesced uint4 copy, bank-balanced)
    {
        const uint4* WT4 = (const uint4*)WT;
        uint4* sWT4 = (uint4*)sWT;
#pragma unroll
        for (int it = 0; it < 8; ++it) sWT4[tid + 256 * it] = WT4[tid + 256 * it];
    }
    __syncthreads();

    const int w = tid >> 6, lane = tid & 63;
    const int m = lane & 15, kq = lane >> 4;
    f32x4 acc[8];
#pragma unroll
    for (int ct = 0; ct < 8; ++ct) acc[ct] = (f32x4)0.f;

    const int r = w * 16 + m;  // r&7 == m&7
#pragma unroll
    for (int ks = 0; ks < 4; ++ks) {
        const bf16x8 a = *(const bf16x8*)&sX[r * 16 + ((kq + 4 * ks) ^ (m & 7))];
#pragma unroll
        for (int ct = 0; ct < 8; ++ct) {
            const int n = ct * 16 + m;  // n&7 == m&7
            const bf16x8 b = *(const bf16x8*)&sWT[n * 128 + (((kq + 4 * ks) ^ (m & 7)) * 8)];
            acc[ct] = __builtin_amdgcn_mfma_f32_16x16x32_bf16(a, b, acc[ct], 0, 0, 0);
        }
    }

    float att[8];
#pragma unroll
    for (int h = 0; h < 4; ++h) {
        att[2 * h]     = attn[h * 32 + m];
        att[2 * h + 1] = attn[h * 32 + 16 + m];
    }
#pragma unroll
    for (int reg = 0; reg < 4; ++reg) {
        const int grow = row0 + w * 16 + kq * 4 + reg;
        const bool ok = grow < nrows;
        float p0 = acc[0][reg] * att[0] + acc[1][reg] * att[1];
        float p1 = acc[2][reg] * att[2] + acc[3][reg] * att[3];
        float p2 = acc[4][reg] * att[4] + acc[5][reg] * att[5];
        float p3 = acc[6][reg] * att[6] + acc[7][reg] * att[7];
#pragma unroll
        for (int d = 1; d < 16; d <<= 1) {
            p0 += __shfl_xor(p0, d);
            p1 += __shfl_xor(p1, d);
            p2 += __shfl_xor(p2, d);
            p3 += __shfl_xor(p3, d);
        }
        if (ok) {
#pragma unroll
            for (int ct = 0; ct < 8; ++ct)
                feats_bf[grow * 128 + ct * 16 + m] = (ushort)f2bf(acc[ct][reg]);
            if (m == 0)
                ((float4*)alphav)[grow] = make_float4(p0, p1, p2, p3);
        }
    }
}

// ---------------------------------------------------------------------------
// K3: edge CSR from sorted edge_idx.
__global__ void csr_kernel(const int* __restrict__ eidx, int* __restrict__ edge_start)
{
    const int i = blockIdx.x * 256 + threadIdx.x;
    if (i >= NINC) return;
    const int cur  = eidx[i];
    const int prev = (i == 0) ? -1 : eidx[i - 1];
    for (int e = prev + 1; e <= cur; ++e) edge_start[e] = i;
    if (i == NINC - 1)
        for (int e = cur + 1; e <= NEDGES; ++e) edge_start[e] = NINC;
}

// ---------------------------------------------------------------------------
// Counting-sort bookkeeping for the node side.
__global__ void zero_kernel(int* __restrict__ p, int n)
{
    const int i = blockIdx.x * 256 + threadIdx.x;
    if (i < n) p[i] = 0;
}

__global__ void hist_kernel(const int* __restrict__ nidx, int* __restrict__ cnt)
{
    const int i = blockIdx.x * 256 + threadIdx.x;
    if (i < NINC) atomicAdd(&cnt[nidx[i]], 1);
}

__global__ __launch_bounds__(256) void assign_kernel(
    const int* __restrict__ cnt, int* __restrict__ node_start,
    int* __restrict__ cursor, int* __restrict__ gcursor)
{
    const int n    = blockIdx.x * 256 + threadIdx.x;
    const int lane = threadIdx.x & 63;
    const int c = (n < NNODES) ? cnt[n] : 0;
    int incl = c;
#pragma unroll
    for (int d = 1; d < 64; d <<= 1) {
        const int v = __shfl_up(incl, d);
        if (lane >= d) incl += v;
    }
    const int total = __shfl(incl, 63);
    int base = 0;
    if (lane == 63) base = atomicAdd(gcursor, total);
    base = __shfl(base, 63);
    const int excl = incl - c;
    if (n < NNODES) {
        node_start[n] = base + excl;
        cursor[n]     = base + excl;
    }
}

// ---------------------------------------------------------------------------
// K4: FUSED edge pipeline — one wave per edge:
//   segment softmax (scores cached in regs) + packed (e, bf16-alpha) scatter
//   into node-sorted slots + node->edge aggregation via LDS-broadcast.
__global__ __launch_bounds__(256) void fused_edge_kernel(
    const int* __restrict__ nidx, const int* __restrict__ estart,
    const float* __restrict__ alpha_l, const float* __restrict__ alpha_r,
    const unsigned int* __restrict__ node_feats_bf,
    const unsigned int* __restrict__ edge_feats_bf,
    int* __restrict__ cursor, uint4* __restrict__ packG,
    unsigned int* __restrict__ edge_aggr_bf)
{
    __shared__ uint4 sInc[4][64];  // wave-private broadcast buffer
    const int e_id = (blockIdx.x * 256 + threadIdx.x) >> 6;
    const int lane = threadIdx.x & 63;
    const int w    = (threadIdx.x >> 6) & 3;
    if (e_id >= NEDGES) return;
    const int s = estart[e_id], t = estart[e_id + 1];
    if (s >= t) return;
    const int deg = t - s;
    const float4 ar = ((const float4*)alpha_r)[e_id];

    // ---- pass 1: scores (chunks 0,1 cached in registers), running max
    int    nc0 = 0, nc1 = 0;
    float4 sc0 = make_float4(0.f, 0.f, 0.f, 0.f), sc1 = sc0;
    float m0 = -FLT_MAX, m1 = -FLT_MAX, m2 = -FLT_MAX, m3 = -FLT_MAX;
    if (s + lane < t) {
        nc0 = nidx[s + lane];
        const float4 al = ((const float4*)alpha_l)[nc0];
        sc0 = make_float4(al.x + ar.x, al.y + ar.y, al.z + ar.z, al.w + ar.w);
        m0 = sc0.x; m1 = sc0.y; m2 = sc0.z; m3 = sc0.w;
    }
    if (deg > 64 && s + 64 + lane < t) {
        nc1 = nidx[s + 64 + lane];
        const float4 al = ((const float4*)alpha_l)[nc1];
        sc1 = make_float4(al.x + ar.x, al.y + ar.y, al.z + ar.z, al.w + ar.w);
        m0 = fmaxf(m0, sc1.x); m1 = fmaxf(m1, sc1.y);
        m2 = fmaxf(m2, sc1.z); m3 = fmaxf(m3, sc1.w);
    }
    for (int c = 2; c * 64 < deg; ++c) {  // cold path (deg > 128)
        const int i = s + c * 64 + lane;
        if (i < t) {
            const float4 al = ((const float4*)alpha_l)[nidx[i]];
            m0 = fmaxf(m0, al.x + ar.x); m1 = fmaxf(m1, al.y + ar.y);
            m2 = fmaxf(m2, al.z + ar.z); m3 = fmaxf(m3, al.w + ar.w);
        }
    }
#pragma unroll
    for (int d = 1; d < 64; d <<= 1) {
        m0 = fmaxf(m0, __shfl_xor(m0, d));
        m1 = fmaxf(m1, __shfl_xor(m1, d));
        m2 = fmaxf(m2, __shfl_xor(m2, d));
        m3 = fmaxf(m3, __shfl_xor(m3, d));
    }

    // ---- pass 2: exp + sum (exp overwrites cached scores)
    float s0 = 0.f, s1 = 0.f, s2 = 0.f, s3 = 0.f;
    if (s + lane < t) {
        sc0.x = __expf(sc0.x - m0); sc0.y = __expf(sc0.y - m1);
        sc0.z = __expf(sc0.z - m2); sc0.w = __expf(sc0.w - m3);
        s0 += sc0.x; s1 += sc0.y; s2 += sc0.z; s3 += sc0.w;
    }
    if (deg > 64 && s + 64 + lane < t) {
        sc1.x = __expf(sc1.x - m0); sc1.y = __expf(sc1.y - m1);
        sc1.z = __expf(sc1.z - m2); sc1.w = __expf(sc1.w - m3);
        s0 += sc1.x; s1 += sc1.y; s2 += sc1.z; s3 += sc1.w;
    }
    for (int c = 2; c * 64 < deg; ++c) {
        const int i = s + c * 64 + lane;
        if (i < t) {
            const float4 al = ((const float4*)alpha_l)[nidx[i]];
            s0 += __expf(al.x + ar.x - m0); s1 += __expf(al.y + ar.y - m1);
            s2 += __expf(al.z + ar.z - m2); s3 += __expf(al.w + ar.w - m3);
        }
    }
#pragma unroll
    for (int d = 1; d < 64; d <<= 1) {
        s0 += __shfl_xor(s0, d); s1 += __shfl_xor(s1, d);
        s2 += __shfl_xor(s2, d); s3 += __shfl_xor(s3, d);
    }
    const float i0 = 1.f / s0, i1 = 1.f / s1, i2 = 1.f / s2, i3 = 1.f / s3;

    // ---- pass 3: per chunk: publish (n, bf16-alpha) to LDS, scatter packed
    // (e, bf16-alpha) to global, accumulate n2e via LDS broadcast reads.
    float ax = 0.f, ay = 0.f;
    const int h = lane >> 4;
    for (int c = 0; c * 64 < deg; ++c) {
        const int i = s + c * 64 + lane;
        int nn = 0;
        float4 a4 = make_float4(0.f, 0.f, 0.f, 0.f);
        if (c == 0) {
            nn = nc0;
            a4 = make_float4(sc0.x * i0, sc0.y * i1, sc0.z * i2, sc0.w * i3);
        } else if (c == 1) {
            nn = nc1;
            a4 = make_float4(sc1.x * i0, sc1.y * i1, sc1.z * i2, sc1.w * i3);
        } else if (i < t) {
            nn = nidx[i];
            const float4 al = ((const float4*)alpha_l)[nn];
            a4.x = __expf(al.x + ar.x - m0) * i0; a4.y = __expf(al.y + ar.y - m1) * i1;
            a4.z = __expf(al.z + ar.z - m2) * i2; a4.w = __expf(al.w + ar.w - m3) * i3;
        }
        const unsigned int a01 = f2bf(a4.x) | (f2bf(a4.y) << 16);
        const unsigned int a23 = f2bf(a4.z) | (f2bf(a4.w) << 16);
        if (i < t) {
            const int pos = atomicAdd(&cursor[nn], 1);
            uint4 g4; g4.x = (unsigned)e_id; g4.y = a01; g4.z = a23; g4.w = 0u;
            packG[pos] = g4;
        }
        uint4 l4; l4.x = (unsigned)nn; l4.y = a01; l4.z = a23; l4.w = 0u;
        sInc[w][lane] = l4;
        asm volatile("s_waitcnt lgkmcnt(0)" ::: "memory");
        const int mj = min(64, deg - c * 64);
        int j = 0;
        for (; j + 8 <= mj; j += 8) {
            uint4 p[8]; unsigned int v[8];
#pragma unroll
            for (int u = 0; u < 8; ++u) p[u] = sInc[w][j + u];
#pragma unroll
            for (int u = 0; u < 8; ++u) v[u] = node_feats_bf[p[u].x * 64 + lane];
#pragma unroll
            for (int u = 0; u < 8; ++u) {
                const unsigned int qb = (h & 2) ? p[u].z : p[u].y;
                const float q = bf2f((h & 1) ? (qb >> 16) : (qb & 0xffffu));
                ax = fmaf(bf2f(v[u] & 0xffffu), q, ax);
                ay = fmaf(bf2f(v[u] >> 16), q, ay);
            }
        }
        for (; j < mj; ++j) {
            const uint4 p = sInc[w][j];
            const unsigned int v = node_feats_bf[p.x * 64 + lane];
            const unsigned int qb = (h & 2) ? p.z : p.y;
            const float q = bf2f((h & 1) ? (qb >> 16) : (qb & 0xffffu));
            ax = fmaf(bf2f(v & 0xffffu), q, ax);
            ay = fmaf(bf2f(v >> 16), q, ay);
        }
    }

    const unsigned int ef = edge_feats_bf[e_id * 64 + lane];
    ax += bf2f(ef & 0xffffu);
    ay += bf2f(ef >> 16);
    edge_aggr_bf[e_id * 64 + lane] = f2bf(ax) | (f2bf(ay) << 16);
}

// ---------------------------------------------------------------------------
// K5: edge->node gather. Per-j data is a wave-uniform packed 16B load
// (sequential, L1/L2-hot) — no shfl, no LDS. Unroll-8 for MLP.
__global__ __launch_bounds__(256) void e2n_gather_kernel(
    const uint4* __restrict__ packG, const int* __restrict__ node_start,
    const int* __restrict__ cnt, const unsigned int* __restrict__ edge_aggr_bf,
    const float* __restrict__ bias, float* __restrict__ out)
{
    const int n    = (blockIdx.x * 256 + threadIdx.x) >> 6;
    const int lane = threadIdx.x & 63;
    if (n >= NNODES) return;
    const int s   = node_start[n];
    const int deg = cnt[n];
    const int h = lane >> 4;
    float ax = 0.f, ay = 0.f;
    int j = 0;
    for (; j + 8 <= deg; j += 8) {
        uint4 p[8]; unsigned int v[8];
#pragma unroll
        for (int u = 0; u < 8; ++u) p[u] = packG[s + j + u];
#pragma unroll
        for (int u = 0; u < 8; ++u) v[u] = edge_aggr_bf[p[u].x * 64 + lane];
#pragma unroll
        for (int u = 0; u < 8; ++u) {
            const unsigned int qb = (h & 2) ? p[u].z : p[u].y;
            const float q = bf2f((h & 1) ? (qb >> 16) : (qb & 0xffffu));
            ax = fmaf(bf2f(v[u] & 0xffffu), q, ax);
            ay = fmaf(bf2f(v[u] >> 16), q, ay);
        }
    }
    for (; j < deg; ++j) {
        const uint4 p = packG[s + j];
        const unsigned int v = edge_aggr_bf[p.x * 64 + lane];
        const unsigned int qb = (h & 2) ? p.z : p.y;
        const float q = bf2f((h & 1) ? (qb >> 16) : (qb & 0xffffu));
        ax = fmaf(bf2f(v & 0xffffu), q, ax);
        ay = fmaf(bf2f(v >> 16), q, ay);
    }
    const float2 b = ((const float2*)bias)[lane];
    ((float2*)out)[n * 64 + lane] = make_float2(ax + b.x, ay + b.y);
}

// ---------------------------------------------------------------------------
extern "C" void kernel_launch(void* const* d_in, const int* in_sizes, int n_in,
                              void* d_out, int out_size, void* d_ws, size_t ws_size,
                              hipStream_t stream)
{
    const float* x      = (const float*)d_in[0];
    const float* he     = (const float*)d_in[1];
    const int*   nidx   = (const int*)d_in[2];
    const int*   eidx   = (const int*)d_in[3];
    const float* Wn     = (const float*)d_in[4];
    const float* We     = (const float*)d_in[5];
    const float* attn_l = (const float*)d_in[6];
    const float* attn_r = (const float*)d_in[7];
    const float* bias   = (const float*)d_in[8];
    float* out = (float*)d_out;

    char* ws = (char*)d_ws;
    ushort* node_feats = (ushort*)ws;  ws += (size_t)NNODES * 128 * 2;
    ushort* edge_feats = (ushort*)ws;  ws += (size_t)NEDGES * 128 * 2;
    float* alpha_l     = (float*)ws;   ws += (size_t)NNODES * 4 * 4;
    float* alpha_r     = (float*)ws;   ws += (size_t)NEDGES * 4 * 4;
    unsigned int* edge_aggr = (unsigned int*)ws; ws += (size_t)NEDGES * 64 * 4;
    int*   edge_start  = (int*)ws;     ws += (size_t)(NEDGES + 4) * 4;
    int*   cnt         = (int*)ws;     ws += (size_t)(NNODES + 4) * 4;  // +gcursor
    int*   node_start  = (int*)ws;     ws += (size_t)(NNODES + 4) * 4;
    int*   cursor      = (int*)ws;     ws += (size_t)NNODES * 4;
    uint4* packG       = (uint4*)ws;   ws += (size_t)NINC * 16;
    ushort* WTn        = (ushort*)ws;  ws += (size_t)128 * 128 * 2;
    ushort* WTe        = (ushort*)ws;  ws += (size_t)128 * 128 * 2;
    int*   gcursor     = cnt + NNODES;

    // one-time W^T (bf16, swizzled) for both weight matrices
    wt_prep_kernel<<<16, 256, 0, stream>>>(Wn, We, WTn, WTe);
    // projections + attention scores (bf16 feature tables) via MFMA
    proj_mfma_kernel<<<(NNODES + 63) / 64, 256, 0, stream>>>(x, WTn, attn_l, node_feats, alpha_l, NNODES);
    proj_mfma_kernel<<<(NEDGES + 63) / 64, 256, 0, stream>>>(he, WTe, attn_r, edge_feats, alpha_r, NEDGES);
    // edge CSR (sorted input)
    csr_kernel<<<(NINC + 255) / 256, 256, 0, stream>>>(eidx, edge_start);
    // node counting-sort bookkeeping
    zero_kernel<<<(NNODES + 1 + 255) / 256, 256, 0, stream>>>(cnt, NNODES + 1);
    hist_kernel<<<(NINC + 255) / 256, 256, 0, stream>>>(nidx, cnt);
    assign_kernel<<<(NNODES + 255) / 256, 256, 0, stream>>>(cnt, node_start, cursor, gcursor);
    // fused: softmax + packed alpha scatter + node->edge aggregation
    fused_edge_kernel<<<(NEDGES * 64 + 255) / 256, 256, 0, stream>>>(
        nidx, edge_start, alpha_l, alpha_r, (const unsigned int*)node_feats,
        (const unsigned int*)edge_feats, cursor, packG, edge_aggr);
    // edge->node gather
    e2n_gather_kernel<<<(NNODES * 64 + 255) / 256, 256, 0, stream>>>(
        packG, node_start, cnt, edge_aggr, bias, out);
}

// Round 8
// 218.169 us; speedup vs baseline: 7.0932x; 1.0145x over previous
//
#include <hip/hip_runtime.h>
#include <hip/hip_bf16.h>
#include <float.h>

#define NNODES 100000
#define NEDGES 25000
#define NINC   800000
#define NH     4

typedef short bf16x8 __attribute__((ext_vector_type(8)));
typedef float f32x4  __attribute__((ext_vector_type(4)));

// bf16 <-> f32 helpers (RNE pack, shift unpack)
__device__ __forceinline__ float bf2f(unsigned int u16)
{
    union { unsigned int u; float f; } c;
    c.u = u16 << 16;
    return c.f;
}
__device__ __forceinline__ unsigned int f2bf(float f)
{
    union { float f; unsigned int u; } c;
    c.f = f;
    return (c.u + 0x7FFFu + ((c.u >> 16) & 1u)) >> 16;
}

// ---------------------------------------------------------------------------
// K0: one-time W -> W^T bf16 with the 8-slot XOR swizzle (both matrices).
__global__ void wt_prep_kernel(const float* __restrict__ Wn, const float* __restrict__ We,
                               ushort* __restrict__ WTn, ushort* __restrict__ WTe)
{
    const int gid = blockIdx.x * 256 + threadIdx.x;  // 0..4095
    const float* W = (gid < 2048) ? Wn : We;
    ushort* WT     = (gid < 2048) ? WTn : WTe;
    const int g  = gid & 2047;
    const int n  = g >> 4, kq = g & 15;
    unsigned int pk[8];
#pragma unroll
    for (int u = 0; u < 8; ++u)
        pk[u] = f2bf(W[(kq * 8 + u) * 128 + n]);
    uint4 v;
    v.x = pk[0] | (pk[1] << 16);
    v.y = pk[2] | (pk[3] << 16);
    v.z = pk[4] | (pk[5] << 16);
    v.w = pk[6] | (pk[7] << 16);
    *(uint4*)&WT[n * 128 + ((kq ^ (n & 7)) * 8)] = v;
}

// ---------------------------------------------------------------------------
// K1/K2: MFMA projection. feats[rows,128] = bf16(X[rows,128] @ W[128,128])
// + fused attention score alpha[rows,4]. W^T comes pre-swizzled (wt_prep).
// Epilogue: wave-private LDS transpose -> coalesced uint4 feats stores.
__global__ __launch_bounds__(256, 3) void proj_mfma_kernel(
    const float* __restrict__ X, const ushort* __restrict__ WT,
    const float* __restrict__ attn, ushort* __restrict__ feats_bf,
    float* __restrict__ alphav, int nrows)
{
    __shared__ uint4  sX[64 * 16];     // [row][slot] bf16x8 slots, swizzled
    __shared__ ushort sWT[128 * 128];  // pre-swizzled copy of WT
    const int tid  = threadIdx.x;
    const int row0 = blockIdx.x * 64;

    // stage X -> bf16 LDS (coalesced float4 reads)
#pragma unroll
    for (int it = 0; it < 4; ++it) {
        const int si = tid + 256 * it;         // 0..1023
        const int r = si >> 4, slot = si & 15;
        const int grow = row0 + r;
        float4 v0 = make_float4(0.f, 0.f, 0.f, 0.f), v1 = v0;
        if (grow < nrows) {
            v0 = ((const float4*)X)[grow * 32 + slot * 2];
            v1 = ((const float4*)X)[grow * 32 + slot * 2 + 1];
        }
        uint4 p;
        p.x = f2bf(v0.x) | (f2bf(v0.y) << 16);
        p.y = f2bf(v0.z) | (f2bf(v0.w) << 16);
        p.z = f2bf(v1.x) | (f2bf(v1.y) << 16);
        p.w = f2bf(v1.z) | (f2bf(v1.w) << 16);
        sX[r * 16 + (slot ^ (r & 7))] = p;
    }
    // stage pre-swizzled W^T (clean coalesced uint4 copy)
    {
        const uint4* WT4 = (const uint4*)WT;
        uint4* sWT4 = (uint4*)sWT;
#pragma unroll
        for (int it = 0; it < 8; ++it) sWT4[tid + 256 * it] = WT4[tid + 256 * it];
    }
    __syncthreads();

    const int w = tid >> 6, lane = tid & 63;
    const int m = lane & 15, kq = lane >> 4;
    f32x4 acc[8];
#pragma unroll
    for (int ct = 0; ct < 8; ++ct) acc[ct] = (f32x4)0.f;

    const int r = w * 16 + m;  // r&7 == m&7
#pragma unroll
    for (int ks = 0; ks < 4; ++ks) {
        const bf16x8 a = *(const bf16x8*)&sX[r * 16 + ((kq + 4 * ks) ^ (m & 7))];
#pragma unroll
        for (int ct = 0; ct < 8; ++ct) {
            const int n = ct * 16 + m;  // n&7 == m&7
            const bf16x8 b = *(const bf16x8*)&sWT[n * 128 + (((kq + 4 * ks) ^ (m & 7)) * 8)];
            acc[ct] = __builtin_amdgcn_mfma_f32_16x16x32_bf16(a, b, acc[ct], 0, 0, 0);
        }
    }

    // fused attention scores (before epilogue clobbers nothing; uses acc+shfl)
    float att[8];
#pragma unroll
    for (int h = 0; h < 4; ++h) {
        att[2 * h]     = attn[h * 32 + m];
        att[2 * h + 1] = attn[h * 32 + 16 + m];
    }
#pragma unroll
    for (int reg = 0; reg < 4; ++reg) {
        const int grow = row0 + w * 16 + kq * 4 + reg;
        float p0 = acc[0][reg] * att[0] + acc[1][reg] * att[1];
        float p1 = acc[2][reg] * att[2] + acc[3][reg] * att[3];
        float p2 = acc[4][reg] * att[4] + acc[5][reg] * att[5];
        float p3 = acc[6][reg] * att[6] + acc[7][reg] * att[7];
#pragma unroll
        for (int d = 1; d < 16; d <<= 1) {
            p0 += __shfl_xor(p0, d);
            p1 += __shfl_xor(p1, d);
            p2 += __shfl_xor(p2, d);
            p3 += __shfl_xor(p3, d);
        }
        if (m == 0 && grow < nrows)
            ((float4*)alphav)[grow] = make_float4(p0, p1, p2, p3);
    }

    // epilogue: transpose through this wave's own 4KB region of sX.
    // sT logical [16 rows][128 cols]; 16B slot s stored at s ^ ((row>>2)<<1).
    {
        ushort* sT = (ushort*)&sX[w * 16 * 16];
#pragma unroll
        for (int ct = 0; ct < 8; ++ct) {
#pragma unroll
            for (int reg = 0; reg < 4; ++reg) {
                const int row  = kq * 4 + reg;
                const int phys = (ct * 2 + (m >> 3)) ^ ((row >> 2) << 1);
                sT[row * 128 + phys * 8 + (m & 7)] = (ushort)f2bf(acc[ct][reg]);
            }
        }
        asm volatile("s_waitcnt lgkmcnt(0)" ::: "memory");
#pragma unroll
        for (int p = 0; p < 4; ++p) {
            const int row  = p * 4 + (lane >> 4);
            const int sl   = lane & 15;
            const int phys = sl ^ ((row >> 2) << 1);
            const uint4 v  = *(const uint4*)&sT[row * 128 + phys * 8];
            const int grow = row0 + w * 16 + row;
            if (grow < nrows)
                *(uint4*)&feats_bf[grow * 128 + sl * 8] = v;
        }
    }
}

// ---------------------------------------------------------------------------
// K3: edge CSR from sorted edge_idx + zero node histogram (fused, independent).
__global__ void csr_zero_kernel(const int* __restrict__ eidx, int* __restrict__ edge_start,
                                int* __restrict__ cnt)
{
    const int i = blockIdx.x * 256 + threadIdx.x;
    if (i < NINC) {
        const int cur  = eidx[i];
        const int prev = (i == 0) ? -1 : eidx[i - 1];
        for (int e = prev + 1; e <= cur; ++e) edge_start[e] = i;
        if (i == NINC - 1)
            for (int e = cur + 1; e <= NEDGES; ++e) edge_start[e] = NINC;
    }
    if (i <= NNODES) cnt[i] = 0;  // includes gcursor at cnt[NNODES]
}

__global__ void hist_kernel(const int* __restrict__ nidx, int* __restrict__ cnt)
{
    const int i = blockIdx.x * 256 + threadIdx.x;
    if (i < NINC) atomicAdd(&cnt[nidx[i]], 1);
}

__global__ __launch_bounds__(256) void assign_kernel(
    const int* __restrict__ cnt, int* __restrict__ node_start,
    int* __restrict__ cursor, int* __restrict__ gcursor)
{
    const int n    = blockIdx.x * 256 + threadIdx.x;
    const int lane = threadIdx.x & 63;
    const int c = (n < NNODES) ? cnt[n] : 0;
    int incl = c;
#pragma unroll
    for (int d = 1; d < 64; d <<= 1) {
        const int v = __shfl_up(incl, d);
        if (lane >= d) incl += v;
    }
    const int total = __shfl(incl, 63);
    int base = 0;
    if (lane == 63) base = atomicAdd(gcursor, total);
    base = __shfl(base, 63);
    const int excl = incl - c;
    if (n < NNODES) {
        node_start[n] = base + excl;
        cursor[n]     = base + excl;
    }
}

// ---------------------------------------------------------------------------
// K4: FUSED edge pipeline — one wave per edge (128-thr blocks for balance):
//   segment softmax (regs) + packed (e, bf16-alpha) scatter + n2e via
//   LDS-broadcast reads.
__global__ __launch_bounds__(128) void fused_edge_kernel(
    const int* __restrict__ nidx, const int* __restrict__ estart,
    const float* __restrict__ alpha_l, const float* __restrict__ alpha_r,
    const unsigned int* __restrict__ node_feats_bf,
    const unsigned int* __restrict__ edge_feats_bf,
    int* __restrict__ cursor, uint4* __restrict__ packG,
    unsigned int* __restrict__ edge_aggr_bf)
{
    __shared__ uint4 sInc[2][64];  // wave-private broadcast buffer
    const int e_id = (blockIdx.x * 128 + threadIdx.x) >> 6;
    const int lane = threadIdx.x & 63;
    const int w    = (threadIdx.x >> 6) & 1;
    if (e_id >= NEDGES) return;
    const int s = estart[e_id], t = estart[e_id + 1];
    if (s >= t) return;
    const int deg = t - s;
    const float4 ar = ((const float4*)alpha_r)[e_id];

    // ---- pass 1: scores (chunks 0,1 cached in registers), running max
    int    nc0 = 0, nc1 = 0;
    float4 sc0 = make_float4(0.f, 0.f, 0.f, 0.f), sc1 = sc0;
    float m0 = -FLT_MAX, m1 = -FLT_MAX, m2 = -FLT_MAX, m3 = -FLT_MAX;
    if (s + lane < t) {
        nc0 = nidx[s + lane];
        const float4 al = ((const float4*)alpha_l)[nc0];
        sc0 = make_float4(al.x + ar.x, al.y + ar.y, al.z + ar.z, al.w + ar.w);
        m0 = sc0.x; m1 = sc0.y; m2 = sc0.z; m3 = sc0.w;
    }
    if (deg > 64 && s + 64 + lane < t) {
        nc1 = nidx[s + 64 + lane];
        const float4 al = ((const float4*)alpha_l)[nc1];
        sc1 = make_float4(al.x + ar.x, al.y + ar.y, al.z + ar.z, al.w + ar.w);
        m0 = fmaxf(m0, sc1.x); m1 = fmaxf(m1, sc1.y);
        m2 = fmaxf(m2, sc1.z); m3 = fmaxf(m3, sc1.w);
    }
    for (int c = 2; c * 64 < deg; ++c) {  // cold path (deg > 128)
        const int i = s + c * 64 + lane;
        if (i < t) {
            const float4 al = ((const float4*)alpha_l)[nidx[i]];
            m0 = fmaxf(m0, al.x + ar.x); m1 = fmaxf(m1, al.y + ar.y);
            m2 = fmaxf(m2, al.z + ar.z); m3 = fmaxf(m3, al.w + ar.w);
        }
    }
#pragma unroll
    for (int d = 1; d < 64; d <<= 1) {
        m0 = fmaxf(m0, __shfl_xor(m0, d));
        m1 = fmaxf(m1, __shfl_xor(m1, d));
        m2 = fmaxf(m2, __shfl_xor(m2, d));
        m3 = fmaxf(m3, __shfl_xor(m3, d));
    }

    // ---- pass 2: exp + sum (exp overwrites cached scores)
    float s0 = 0.f, s1 = 0.f, s2 = 0.f, s3 = 0.f;
    if (s + lane < t) {
        sc0.x = __expf(sc0.x - m0); sc0.y = __expf(sc0.y - m1);
        sc0.z = __expf(sc0.z - m2); sc0.w = __expf(sc0.w - m3);
        s0 += sc0.x; s1 += sc0.y; s2 += sc0.z; s3 += sc0.w;
    }
    if (deg > 64 && s + 64 + lane < t) {
        sc1.x = __expf(sc1.x - m0); sc1.y = __expf(sc1.y - m1);
        sc1.z = __expf(sc1.z - m2); sc1.w = __expf(sc1.w - m3);
        s0 += sc1.x; s1 += sc1.y; s2 += sc1.z; s3 += sc1.w;
    }
    for (int c = 2; c * 64 < deg; ++c) {
        const int i = s + c * 64 + lane;
        if (i < t) {
            const float4 al = ((const float4*)alpha_l)[nidx[i]];
            s0 += __expf(al.x + ar.x - m0); s1 += __expf(al.y + ar.y - m1);
            s2 += __expf(al.z + ar.z - m2); s3 += __expf(al.w + ar.w - m3);
        }
    }
#pragma unroll
    for (int d = 1; d < 64; d <<= 1) {
        s0 += __shfl_xor(s0, d); s1 += __shfl_xor(s1, d);
        s2 += __shfl_xor(s2, d); s3 += __shfl_xor(s3, d);
    }
    const float i0 = 1.f / s0, i1 = 1.f / s1, i2 = 1.f / s2, i3 = 1.f / s3;

    // ---- pass 3: per chunk: publish (n, bf16-alpha) to LDS, scatter packed
    // (e, bf16-alpha) to global, accumulate n2e via LDS broadcast reads.
    float ax = 0.f, ay = 0.f;
    const int h = lane >> 4;
    for (int c = 0; c * 64 < deg; ++c) {
        const int i = s + c * 64 + lane;
        int nn = 0;
        float4 a4 = make_float4(0.f, 0.f, 0.f, 0.f);
        if (c == 0) {
            nn = nc0;
            a4 = make_float4(sc0.x * i0, sc0.y * i1, sc0.z * i2, sc0.w * i3);
        } else if (c == 1) {
            nn = nc1;
            a4 = make_float4(sc1.x * i0, sc1.y * i1, sc1.z * i2, sc1.w * i3);
        } else if (i < t) {
            nn = nidx[i];
            const float4 al = ((const float4*)alpha_l)[nn];
            a4.x = __expf(al.x + ar.x - m0) * i0; a4.y = __expf(al.y + ar.y - m1) * i1;
            a4.z = __expf(al.z + ar.z - m2) * i2; a4.w = __expf(al.w + ar.w - m3) * i3;
        }
        const unsigned int a01 = f2bf(a4.x) | (f2bf(a4.y) << 16);
        const unsigned int a23 = f2bf(a4.z) | (f2bf(a4.w) << 16);
        if (i < t) {
            const int pos = atomicAdd(&cursor[nn], 1);
            uint4 g4; g4.x = (unsigned)e_id; g4.y = a01; g4.z = a23; g4.w = 0u;
            packG[pos] = g4;
        }
        uint4 l4; l4.x = (unsigned)nn; l4.y = a01; l4.z = a23; l4.w = 0u;
        sInc[w][lane] = l4;
        asm volatile("s_waitcnt lgkmcnt(0)" ::: "memory");
        const int mj = min(64, deg - c * 64);
        int j = 0;
        for (; j + 8 <= mj; j += 8) {
            uint4 p[8]; unsigned int v[8];
#pragma unroll
            for (int u = 0; u < 8; ++u) p[u] = sInc[w][j + u];
#pragma unroll
            for (int u = 0; u < 8; ++u) v[u] = node_feats_bf[p[u].x * 64 + lane];
#pragma unroll
            for (int u = 0; u < 8; ++u) {
                const unsigned int qb = (h & 2) ? p[u].z : p[u].y;
                const float q = bf2f((h & 1) ? (qb >> 16) : (qb & 0xffffu));
                ax = fmaf(bf2f(v[u] & 0xffffu), q, ax);
                ay = fmaf(bf2f(v[u] >> 16), q, ay);
            }
        }
        for (; j < mj; ++j) {
            const uint4 p = sInc[w][j];
            const unsigned int v = node_feats_bf[p.x * 64 + lane];
            const unsigned int qb = (h & 2) ? p.z : p.y;
            const float q = bf2f((h & 1) ? (qb >> 16) : (qb & 0xffffu));
            ax = fmaf(bf2f(v & 0xffffu), q, ax);
            ay = fmaf(bf2f(v >> 16), q, ay);
        }
    }

    const unsigned int ef = edge_feats_bf[e_id * 64 + lane];
    ax += bf2f(ef & 0xffffu);
    ay += bf2f(ef >> 16);
    edge_aggr_bf[e_id * 64 + lane] = f2bf(ax) | (f2bf(ay) << 16);
}

// ---------------------------------------------------------------------------
// K5: edge->node gather. Wave-uniform packed 16B reads (sequential), unroll-8,
// nontemporal output stores (out never re-read; don't pollute L2).
__global__ __launch_bounds__(128) void e2n_gather_kernel(
    const uint4* __restrict__ packG, const int* __restrict__ node_start,
    const int* __restrict__ cnt, const unsigned int* __restrict__ edge_aggr_bf,
    const float* __restrict__ bias, float* __restrict__ out)
{
    const int n    = (blockIdx.x * 128 + threadIdx.x) >> 6;
    const int lane = threadIdx.x & 63;
    if (n >= NNODES) return;
    const int s   = node_start[n];
    const int deg = cnt[n];
    const int h = lane >> 4;
    float ax = 0.f, ay = 0.f;
    int j = 0;
    for (; j + 8 <= deg; j += 8) {
        uint4 p[8]; unsigned int v[8];
#pragma unroll
        for (int u = 0; u < 8; ++u) p[u] = packG[s + j + u];
#pragma unroll
        for (int u = 0; u < 8; ++u) v[u] = edge_aggr_bf[p[u].x * 64 + lane];
#pragma unroll
        for (int u = 0; u < 8; ++u) {
            const unsigned int qb = (h & 2) ? p[u].z : p[u].y;
            const float q = bf2f((h & 1) ? (qb >> 16) : (qb & 0xffffu));
            ax = fmaf(bf2f(v[u] & 0xffffu), q, ax);
            ay = fmaf(bf2f(v[u] >> 16), q, ay);
        }
    }
    for (; j < deg; ++j) {
        const uint4 p = packG[s + j];
        const unsigned int v = edge_aggr_bf[p.x * 64 + lane];
        const unsigned int qb = (h & 2) ? p.z : p.y;
        const float q = bf2f((h & 1) ? (qb >> 16) : (qb & 0xffffu));
        ax = fmaf(bf2f(v & 0xffffu), q, ax);
        ay = fmaf(bf2f(v >> 16), q, ay);
    }
    const float2 b = ((const float2*)bias)[lane];
    union { float2 f2; unsigned long long u64; } o;
    o.f2 = make_float2(ax + b.x, ay + b.y);
    __builtin_nontemporal_store(o.u64, (unsigned long long*)&((float2*)out)[n * 64 + lane]);
}

// ---------------------------------------------------------------------------
extern "C" void kernel_launch(void* const* d_in, const int* in_sizes, int n_in,
                              void* d_out, int out_size, void* d_ws, size_t ws_size,
                              hipStream_t stream)
{
    const float* x      = (const float*)d_in[0];
    const float* he     = (const float*)d_in[1];
    const int*   nidx   = (const int*)d_in[2];
    const int*   eidx   = (const int*)d_in[3];
    const float* Wn     = (const float*)d_in[4];
    const float* We     = (const float*)d_in[5];
    const float* attn_l = (const float*)d_in[6];
    const float* attn_r = (const float*)d_in[7];
    const float* bias   = (const float*)d_in[8];
    float* out = (float*)d_out;

    char* ws = (char*)d_ws;
    ushort* node_feats = (ushort*)ws;  ws += (size_t)NNODES * 128 * 2;
    ushort* edge_feats = (ushort*)ws;  ws += (size_t)NEDGES * 128 * 2;
    float* alpha_l     = (float*)ws;   ws += (size_t)NNODES * 4 * 4;
    float* alpha_r     = (float*)ws;   ws += (size_t)NEDGES * 4 * 4;
    unsigned int* edge_aggr = (unsigned int*)ws; ws += (size_t)NEDGES * 64 * 4;
    int*   edge_start  = (int*)ws;     ws += (size_t)(NEDGES + 4) * 4;
    int*   cnt         = (int*)ws;     ws += (size_t)(NNODES + 4) * 4;  // +gcursor
    int*   node_start  = (int*)ws;     ws += (size_t)(NNODES + 4) * 4;
    int*   cursor      = (int*)ws;     ws += (size_t)NNODES * 4;
    uint4* packG       = (uint4*)ws;   ws += (size_t)NINC * 16;
    ushort* WTn        = (ushort*)ws;  ws += (size_t)128 * 128 * 2;
    ushort* WTe        = (ushort*)ws;  ws += (size_t)128 * 128 * 2;
    int*   gcursor     = cnt + NNODES;

    // one-time W^T (bf16, swizzled) for both weight matrices
    wt_prep_kernel<<<16, 256, 0, stream>>>(Wn, We, WTn, WTe);
    // projections + attention scores (bf16 feature tables) via MFMA
    proj_mfma_kernel<<<(NNODES + 63) / 64, 256, 0, stream>>>(x, WTn, attn_l, node_feats, alpha_l, NNODES);
    proj_mfma_kernel<<<(NEDGES + 63) / 64, 256, 0, stream>>>(he, WTe, attn_r, edge_feats, alpha_r, NEDGES);
    // edge CSR + zero histogram (fused)
    csr_zero_kernel<<<(NINC + 255) / 256, 256, 0, stream>>>(eidx, edge_start, cnt);
    hist_kernel<<<(NINC + 255) / 256, 256, 0, stream>>>(nidx, cnt);
    assign_kernel<<<(NNODES + 255) / 256, 256, 0, stream>>>(cnt, node_start, cursor, gcursor);
    // fused: softmax + packed alpha scatter + node->edge aggregation
    fused_edge_kernel<<<(NEDGES * 64 + 127) / 128, 128, 0, stream>>>(
        nidx, edge_start, alpha_l, alpha_r, (const unsigned int*)node_feats,
        (const unsigned int*)edge_feats, cursor, packG, edge_aggr);
    // edge->node gather
    e2n_gather_kernel<<<(NNODES * 64 + 127) / 128, 128, 0, stream>>>(
        packG, node_start, cnt, edge_aggr, bias, out);
}